// Round 8
// baseline (601.264 us; speedup 1.0000x reference)
//
#include <hip/hip_runtime.h>
#include <cstdint>
#include <cstddef>

#define SEQ     2048
#define NBATCH  2
#define BL      (NBATCH*SEQ)     // 4096
#define DMODEL  2048
#define DINNER  4096
#define DSTATE  128
#define HEADDIM 64
#define NHEADS  64
#define DXBC    4352
#define DPROJ   8512
#define NPAD    8704             // padded D_IN_PROJ (34*256)
#define NCHUNK  16
#define CHUNKL  128

typedef __bf16 bf16x8_t __attribute__((ext_vector_type(8)));
typedef float f32x4_t __attribute__((ext_vector_type(4)));
typedef unsigned short u16x8_t __attribute__((ext_vector_type(8)));
typedef unsigned short u16x4_t __attribute__((ext_vector_type(4)));
typedef __attribute__((address_space(1))) unsigned int as1_u32;
typedef __attribute__((address_space(3))) unsigned int as3_u32;

__device__ __forceinline__ unsigned short f2bf(float f) {
  unsigned u = __builtin_bit_cast(unsigned, f);
  u += 0x7FFFu + ((u >> 16) & 1u);
  return (unsigned short)(u >> 16);
}
__device__ __forceinline__ float bf2f(unsigned short h) {
  unsigned u = ((unsigned)h) << 16;
  return __builtin_bit_cast(float, u);
}
__device__ __forceinline__ void gload16(const void* g, void* l) {
  __builtin_amdgcn_global_load_lds((const as1_u32*)g, (as3_u32*)l, 16, 0, 0);
}
__device__ __forceinline__ f32x4_t mfma16(u16x8_t a, u16x8_t b, f32x4_t c) {
  return __builtin_amdgcn_mfma_f32_16x16x32_bf16(
      __builtin_bit_cast(bf16x8_t, a), __builtin_bit_cast(bf16x8_t, b), c, 0, 0, 0);
}
__device__ __forceinline__ float siluf(float x) { return x / (1.f + __expf(-x)); }

// ---------------- converts ----------------
__global__ __launch_bounds__(256) void cvt_kernel(const float* __restrict__ src,
                                                  unsigned short* __restrict__ dst, int n) {
  int idx = (blockIdx.x * 256 + threadIdx.x) * 4;
  if (idx >= n) return;
  float4 v = *(const float4*)&src[idx];
  u16x4_t o; o[0] = f2bf(v.x); o[1] = f2bf(v.y); o[2] = f2bf(v.z); o[3] = f2bf(v.w);
  *(u16x4_t*)&dst[idx] = o;
}

__global__ __launch_bounds__(256) void cvt_win_kernel(const float* __restrict__ W,
                                                      unsigned short* __restrict__ dst) {
  int idx = (blockIdx.x * 256 + threadIdx.x) * 4;
  if (idx >= NPAD * DMODEL) return;
  int e = idx / DMODEL;
  u16x4_t o;
  if (e < DPROJ) {
    float4 v = *(const float4*)&W[idx];
    o[0] = f2bf(v.x); o[1] = f2bf(v.y); o[2] = f2bf(v.z); o[3] = f2bf(v.w);
  } else {
    o[0] = 0; o[1] = 0; o[2] = 0; o[3] = 0;
  }
  *(u16x4_t*)&dst[idx] = o;
}

// ---------------- GEMM: C[M][N] = A[M][K] * B[N][K]^T, bf16 in ----------------
// Two measured-best schedules, selected per call site:
//  FINE=false (GEMM1, WM=8): R4 schedule — 4-buf ring, one barrier/tile,
//    counted vmcnt (2 tiles in flight), reads+stage interleaved with setprio'd
//    MFMA clusters. Measured 179 us, MfmaUtil 35%, 0 bank conflicts.
//  FINE=true (GEMM2, WM=4): R5 fine schedule — per-phase barrier + lgkmcnt(0)
//    + sched_barrier before each MFMA cluster (early-issue ds_reads complete
//    during barrier wait). Measured best for the K=4096-deep skinny tile.
template <int WM, bool BF16OUT, bool FINE>
__global__ __launch_bounds__(512, 2) void gemm256_kernel(const unsigned short* __restrict__ A,
                                                         const unsigned short* __restrict__ B,
                                                         void* __restrict__ Cp,
                                                         int M, int N, int K, int gx) {
  constexpr int BM  = 32 * WM;
  constexpr int AUB = BM * 64;          // A-unit bytes per K-tile
  constexpr int BUB = 16384;            // B-unit bytes (256 rows x 64B)
  constexpr int BUF = AUB + BUB;
  constexpr int LA  = AUB / 8192;       // gload instrs per thread, A unit
  constexpr int LB  = 2;
  constexpr int LT  = LA + LB;          // loads per tile
  __shared__ __attribute__((aligned(16))) char lds[4 * BUF];

  const int nwg = gridDim.x;
  const int q8 = nwg >> 3;
  const int lid = blockIdx.x;
  const int newid = (lid & 7) * q8 + (lid >> 3);     // bijective XCD chunking
  const int band = newid / (gx * 4);
  const int idx  = newid % (gx * 4);
  const int n0 = (idx >> 2) * 256;
  const int m0 = (band * 4 + (idx & 3)) * BM;

  const int t = threadIdx.x, lane = t & 63, w = t >> 6;
  const int wm = w >> 2, wn = w & 3;                 // 2 x 4 waves
  const int NK = K >> 5;
  const int kslot = (lane >> 4) * 16;                // 16B col-slot

  f32x4_t acc[WM][4];
#pragma unroll
  for (int i = 0; i < WM; ++i)
#pragma unroll
    for (int j = 0; j < 4; ++j) acc[i][j] = (f32x4_t){0.f, 0.f, 0.f, 0.f};

  auto stage_unit = [&](int u) {
    if (u >= 2 * NK) return;
    const int Tt = u >> 1;
    char* base = lds + (Tt & 3) * BUF + ((u & 1) ? AUB : 0);
    const unsigned short* G = (u & 1) ? B : A;
    const int g0 = (u & 1) ? n0 : m0;
    const int k0 = Tt << 5;
    if (u & 1) {
#pragma unroll
      for (int i = 0; i < LB; ++i) {
        int o = i * 8192 + t * 16;
        int row = o >> 6;
        int cb = (o & 63) ^ (((row >> 1) & 3) << 4);     // inverse-swizzle source
        gload16(&G[(size_t)(g0 + row) * K + k0 + (cb >> 1)], base + o);
      }
    } else {
#pragma unroll
      for (int i = 0; i < LA; ++i) {
        int o = i * 8192 + t * 16;
        int row = o >> 6;
        int cb = (o & 63) ^ (((row >> 1) & 3) << 4);
        gload16(&G[(size_t)(g0 + row) * K + k0 + (cb >> 1)], base + o);
      }
    }
  };
  auto rdA = [&](int bq, int mr) -> u16x8_t {
    int row = wm * (BM / 2) + mr * 16 + (lane & 15);
    int byte = bq * BUF + row * 64 + (kslot ^ (((row >> 1) & 3) << 4));
    return *(const u16x8_t*)(lds + byte);
  };
  auto rdB = [&](int bq, int nr) -> u16x8_t {
    int row = wn * 64 + nr * 16 + (lane & 15);
    int byte = bq * BUF + AUB + row * 64 + (kslot ^ (((row >> 1) & 3) << 4));
    return *(const u16x8_t*)(lds + byte);
  };

  // prologue: tiles 0,1,2 in flight (3*LT loads)
#pragma unroll
  for (int u = 0; u < 6; ++u) stage_unit(u);

  if constexpr (FINE) {
    if constexpr (WM == 8) asm volatile("s_waitcnt vmcnt(8)" ::: "memory");
    else                   asm volatile("s_waitcnt vmcnt(6)" ::: "memory");
    asm volatile("" ::: "memory");
    __builtin_amdgcn_s_barrier();
  }

  for (int T = 0; T < NK; ++T) {
    const int bq = T & 3;
    u16x8_t af[WM], bfr[4];
    if constexpr (!FINE) {
      // ---- R4 schedule: one barrier per tile ----
      if (T <= NK - 3)      { if constexpr (LT == 4) asm volatile("s_waitcnt vmcnt(8)" ::: "memory");
                              else                   asm volatile("s_waitcnt vmcnt(6)" ::: "memory"); }
      else if (T == NK - 2) { if constexpr (LT == 4) asm volatile("s_waitcnt vmcnt(4)" ::: "memory");
                              else                   asm volatile("s_waitcnt vmcnt(3)" ::: "memory"); }
      else                  asm volatile("s_waitcnt vmcnt(0)" ::: "memory");
      __builtin_amdgcn_s_barrier();
      asm volatile("" ::: "memory");
      __builtin_amdgcn_sched_barrier(0);

#pragma unroll
      for (int mr = 0; mr < WM; ++mr) af[mr] = rdA(bq, mr);
      bfr[0] = rdB(bq, 0);
      bfr[1] = rdB(bq, 1);
      stage_unit(2 * T + 6);
      __builtin_amdgcn_s_setprio(1);
#pragma unroll
      for (int mr = 0; mr < WM; ++mr) {
        acc[mr][0] = mfma16(af[mr], bfr[0], acc[mr][0]);
        acc[mr][1] = mfma16(af[mr], bfr[1], acc[mr][1]);
      }
      __builtin_amdgcn_s_setprio(0);
      bfr[2] = rdB(bq, 2);
      bfr[3] = rdB(bq, 3);
      stage_unit(2 * T + 7);
      __builtin_amdgcn_s_setprio(1);
#pragma unroll
      for (int mr = 0; mr < WM; ++mr) {
        acc[mr][2] = mfma16(af[mr], bfr[2], acc[mr][2]);
        acc[mr][3] = mfma16(af[mr], bfr[3], acc[mr][3]);
      }
      __builtin_amdgcn_s_setprio(0);
    } else {
      // ---- R5 fine schedule: per-phase barrier + lgkmcnt(0) ----
      // phase A: issue reads early, stage, sync, MFMA cluster (nr 0,1)
#pragma unroll
      for (int mr = 0; mr < WM; ++mr) af[mr] = rdA(bq, mr);
      bfr[0] = rdB(bq, 0);
      bfr[1] = rdB(bq, 1);
      stage_unit(2 * T + 6);
      asm volatile("" ::: "memory");
      __builtin_amdgcn_s_barrier();
      asm volatile("s_waitcnt lgkmcnt(0)" ::: "memory");
      __builtin_amdgcn_sched_barrier(0);
      __builtin_amdgcn_s_setprio(1);
#pragma unroll
      for (int mr = 0; mr < WM; ++mr) {
        acc[mr][0] = mfma16(af[mr], bfr[0], acc[mr][0]);
        acc[mr][1] = mfma16(af[mr], bfr[1], acc[mr][1]);
      }
      __builtin_amdgcn_s_setprio(0);
      asm volatile("" ::: "memory");
      __builtin_amdgcn_s_barrier();
      // phase B: reads, stage, MFMA cluster (nr 2,3), tile-boundary sync
      bfr[2] = rdB(bq, 2);
      bfr[3] = rdB(bq, 3);
      stage_unit(2 * T + 7);
      asm volatile("s_waitcnt lgkmcnt(0)" ::: "memory");
      __builtin_amdgcn_sched_barrier(0);
      __builtin_amdgcn_s_setprio(1);
#pragma unroll
      for (int mr = 0; mr < WM; ++mr) {
        acc[mr][2] = mfma16(af[mr], bfr[2], acc[mr][2]);
        acc[mr][3] = mfma16(af[mr], bfr[3], acc[mr][3]);
      }
      __builtin_amdgcn_s_setprio(0);
      if (T < NK - 3) {
        if constexpr (WM == 8) asm volatile("s_waitcnt vmcnt(8)" ::: "memory");
        else                   asm volatile("s_waitcnt vmcnt(6)" ::: "memory");
      } else if (T == NK - 3) {
        if constexpr (WM == 8) asm volatile("s_waitcnt vmcnt(4)" ::: "memory");
        else                   asm volatile("s_waitcnt vmcnt(3)" ::: "memory");
      } else if (T == NK - 2) {
        asm volatile("s_waitcnt vmcnt(0)" ::: "memory");
      }
      asm volatile("" ::: "memory");
      __builtin_amdgcn_s_barrier();
    }
  }

  // epilogue
#pragma unroll
  for (int mr = 0; mr < WM; ++mr) {
    const int mbase = m0 + wm * (BM / 2) + mr * 16 + (lane >> 4) * 4;
#pragma unroll
    for (int nr = 0; nr < 4; ++nr) {
      const int n = n0 + wn * 64 + nr * 16 + (lane & 15);
#pragma unroll
      for (int r = 0; r < 4; ++r) {
        if (BF16OUT) ((unsigned short*)Cp)[(size_t)(mbase + r) * N + n] = f2bf(acc[mr][nr][r]);
        else         ((float*)Cp)[(size_t)(mbase + r) * N + n] = acc[mr][nr][r];
      }
    }
  }
}

// -------- depthwise causal conv + silu, 8 channels/thread (bf16 vec) --------
__global__ __launch_bounds__(256) void conv_kernel(const unsigned short* __restrict__ zx,
                                                   const float* __restrict__ conv_w,
                                                   const float* __restrict__ conv_b,
                                                   unsigned short* __restrict__ xc) {
  int idx = blockIdx.x * 256 + threadIdx.x;
  if (idx >= BL * (DXBC / 8)) return;
  int e8 = (idx % (DXBC / 8)) * 8;
  int bl = idx / (DXBC / 8);
  int l = bl % SEQ, b = bl / SEQ;
  float acc[8];
#pragma unroll
  for (int j = 0; j < 8; ++j) acc[j] = conv_b[e8 + j];
  const unsigned short* zrow = zx + (size_t)b * SEQ * NPAD + DINNER + e8;
#pragma unroll
  for (int wi = 0; wi < 4; ++wi) {
    int ll = l - 3 + wi;
    if (ll >= 0) {
      u16x8_t v = *(const u16x8_t*)(zrow + (size_t)ll * NPAD);
#pragma unroll
      for (int j = 0; j < 8; ++j) acc[j] += bf2f(v[j]) * conv_w[(e8 + j) * 4 + wi];
    }
  }
  u16x8_t o;
#pragma unroll
  for (int j = 0; j < 8; ++j) o[j] = f2bf(siluf(acc[j]));
  *(u16x8_t*)(xc + (size_t)bl * DXBC + e8) = o;
}

// ---------------- dt softplus + per-chunk cumsum of dA ----------------
__global__ __launch_bounds__(128) void dt_kernel(const unsigned short* __restrict__ zx,
                                                 const float* __restrict__ dt_bias,
                                                 const float* __restrict__ A_log,
                                                 float* __restrict__ dt_soft,   // [b][h][l]
                                                 float* __restrict__ Acs,       // [b][h][c][128]
                                                 float* __restrict__ cdecay) {  // [b][h][c]
  int blk = blockIdx.x;                       // (b*64+h)*16+c
  int c = blk & 15, h = (blk >> 4) & 63, b = blk >> 10;
  int i = threadIdx.x;
  int l = c * CHUNKL + i;
  float raw = bf2f(zx[((size_t)b * SEQ + l) * NPAD + (DINNER + DXBC) + h]) + dt_bias[h];
  float dt = (raw > 20.f) ? raw : log1pf(__expf(raw));
  dt_soft[((size_t)b * 64 + h) * SEQ + l] = dt;
  float A = -__expf(A_log[h]);
  __shared__ float sbuf[128];
  sbuf[i] = dt * A;
  __syncthreads();
  for (int ofs = 1; ofs < 128; ofs <<= 1) {
    float v = (i >= ofs) ? sbuf[i - ofs] : 0.f;
    __syncthreads();
    sbuf[i] += v;
    __syncthreads();
  }
  float cs = sbuf[i];
  Acs[(((size_t)b * 64 + h) * 16 + c) * 128 + i] = cs;
  if (i == 127) cdecay[((size_t)b * 64 + h) * 16 + c] = __expf(cs);
}

// ---------------- xdt^T builder: xdtT[b][h][p][l] = x[b,l,h*64+p]*dt ----------
__global__ __launch_bounds__(256) void xdt_kernel(const unsigned short* __restrict__ xc,
                                                  const float* __restrict__ dt_soft,
                                                  unsigned short* __restrict__ xdtT) {
  int blk = blockIdx.x;                       // (b*64+h)*16+lt
  int lt = blk & 15, h = (blk >> 4) & 63, b = blk >> 10;
  __shared__ unsigned short tile[128][66];
  __shared__ float dts[128];
  int t = threadIdx.x;
  const unsigned short* xg = xc + ((size_t)b * SEQ + lt * 128) * DXBC + h * 64;
#pragma unroll
  for (int k = 0; k < 32; ++k) {
    int idx = t + k * 256;
    int row = idx >> 6, col = idx & 63;
    tile[row][col] = xg[(size_t)row * DXBC + col];
  }
  if (t < 128) dts[t] = dt_soft[((size_t)b * 64 + h) * SEQ + lt * 128 + t];
  __syncthreads();
  unsigned short* xo = xdtT + (((size_t)b * 64 + h) * 64) * SEQ + lt * 128;
#pragma unroll
  for (int k = 0; k < 32; ++k) {
    int idx = t + k * 256;
    int p = idx >> 7, j = idx & 127;
    xo[(size_t)p * SEQ + j] = f2bf(bf2f(tile[j][p]) * dts[j]);
  }
}

// ---------------- B transpose from xc: BT[b][n][l] ----------------
__global__ __launch_bounds__(256) void btr_kernel(const unsigned short* __restrict__ xc,
                                                  unsigned short* __restrict__ BT) {
  int blk = blockIdx.x;                       // b*16+lt
  int lt = blk & 15, b = blk >> 4;
  __shared__ unsigned short tile[128][129];
  int t = threadIdx.x;
  const unsigned short* src = xc + ((size_t)b * SEQ + lt * 128) * DXBC + DINNER;
#pragma unroll
  for (int k = 0; k < 64; ++k) {
    int idx = t + k * 256;
    int j = idx >> 7, n = idx & 127;
    tile[j][n] = src[(size_t)j * DXBC + n];
  }
  __syncthreads();
  unsigned short* dst = BT + (size_t)b * 128 * SEQ + lt * 128;
#pragma unroll
  for (int k = 0; k < 64; ++k) {
    int idx = t + k * 256;
    int n = idx >> 7, j = idx & 127;
    dst[(size_t)n * SEQ + j] = tile[j][n];
  }
}

// ---------------- SSD per-chunk states: states[b][c][h][p][n] ----------------
__global__ __launch_bounds__(256) void ssd_states_kernel(const unsigned short* __restrict__ BT,
                                                         const unsigned short* __restrict__ xdtT,
                                                         const float* __restrict__ Acs,
                                                         float* __restrict__ states) {
  int blk = blockIdx.x;                       // ((b*16+c)*64+h)
  int h = blk & 63, c = (blk >> 6) & 15, b = blk >> 10;
  __shared__ unsigned short BTs[128 * 128];   // [n][j]
  __shared__ unsigned short xs[64 * 128];     // [p][j]
  __shared__ float dec[128];
  int t = threadIdx.x, lane = t & 63, w = t >> 6, wr = w >> 1, wc = w & 1;
  int srow = t >> 4, scol = (t & 15) * 8;
  const unsigned short* BTb = BT + (size_t)b * 128 * SEQ + c * 128;
#pragma unroll
  for (int s = 0; s < 8; ++s) {
    int r = s * 16 + srow;
    gload16(&BTb[(size_t)r * SEQ + scol], &BTs[r * 128 + scol]);
  }
  const unsigned short* xb = xdtT + (((size_t)b * 64 + h) * 64) * SEQ + c * 128;
#pragma unroll
  for (int s = 0; s < 4; ++s) {
    int r = s * 16 + srow;
    gload16(&xb[(size_t)r * SEQ + scol], &xs[r * 128 + scol]);
  }
  const float* acsr = Acs + (((size_t)b * 64 + h) * 16 + c) * 128;
  float alast = acsr[127];
  if (t < 128) dec[t] = __expf(alast - acsr[t]);
  __syncthreads();

  f32x4_t acc[2][4];
#pragma unroll
  for (int i = 0; i < 2; ++i)
#pragma unroll
    for (int j = 0; j < 4; ++j) acc[i][j] = (f32x4_t){0.f, 0.f, 0.f, 0.f};
#pragma unroll
  for (int ks = 0; ks < 4; ++ks) {
    const int kk = ks * 32 + (lane >> 4) * 8;
    float d8[8];
#pragma unroll
    for (int e = 0; e < 8; ++e) d8[e] = dec[kk + e];
    u16x8_t af[2], bfr[4];
#pragma unroll
    for (int i = 0; i < 2; ++i) {
      u16x8_t raw = *(const u16x8_t*)&xs[(wr * 32 + i * 16 + (lane & 15)) * 128 + kk];
      u16x8_t sc;
#pragma unroll
      for (int e = 0; e < 8; ++e) sc[e] = f2bf(bf2f(raw[e]) * d8[e]);
      af[i] = sc;
    }
#pragma unroll
    for (int j = 0; j < 4; ++j)
      bfr[j] = *(const u16x8_t*)&BTs[(wc * 64 + j * 16 + (lane & 15)) * 128 + kk];
#pragma unroll
    for (int i = 0; i < 2; ++i)
#pragma unroll
      for (int j = 0; j < 4; ++j) acc[i][j] = mfma16(af[i], bfr[j], acc[i][j]);
  }
  float* so = states + ((((size_t)b * 16 + c) * 64 + h) * 64) * 128;
#pragma unroll
  for (int i = 0; i < 2; ++i) {
    int pbase = wr * 32 + i * 16 + (lane >> 4) * 4;
#pragma unroll
    for (int j = 0; j < 4; ++j) {
      int n = wc * 64 + j * 16 + (lane & 15);
#pragma unroll
      for (int r = 0; r < 4; ++r) so[(size_t)(pbase + r) * 128 + n] = acc[i][j][r];
    }
  }
}

// ---------------- inter-chunk scan (1024 blocks, 4 elem/thread) ----------------
__global__ __launch_bounds__(256) void ssd_scan_kernel(const float* __restrict__ states,
                                                       const float* __restrict__ cdecay,
                                                       unsigned short* __restrict__ prevb) {
  int blk = blockIdx.x;                       // ((b*64+h)*8 + s)
  int s = blk & 7, h = (blk >> 3) & 63, b = blk >> 9;
  int t = threadIdx.x;
  float carry[4] = {0.f, 0.f, 0.f, 0.f};
  const float* cd = cdecay + ((size_t)b * 64 + h) * 16;
  for (int c = 0; c < 16; ++c) {
    const float* sp = states + (((size_t)(b * 16 + c) * 64 + h) * 64) * 128;
    unsigned short* pp = prevb + (((size_t)(b * 16 + c) * 64 + h) * 64) * 128;
    float d = cd[c];
#pragma unroll
    for (int k = 0; k < 4; ++k) {
      int e = s * 1024 + k * 256 + t;
      pp[e] = f2bf(carry[k]);
      carry[k] = carry[k] * d + sp[e];
    }
  }
}

// ---------------- SSD Y = Y_diag + Y_off + D*x (bf16 out) ----------------
__global__ __launch_bounds__(256) void ssd_y_kernel(const unsigned short* __restrict__ xc,
                                                    const unsigned short* __restrict__ xdtT,
                                                    const unsigned short* __restrict__ prevb,
                                                    const float* __restrict__ Acs,
                                                    const float* __restrict__ Dp,
                                                    unsigned short* __restrict__ Y) {
  int blk = blockIdx.x;                       // ((b*16+c)*64+h)
  int h = blk & 63, c = (blk >> 6) & 15, b = blk >> 10;
  __shared__ unsigned short Bs[128 * 128];    // [j][n], reused as M[i][j]
  __shared__ unsigned short Cs[128 * 128];    // [i][n]
  __shared__ unsigned short xs[64 * 128];     // [p][j]
  __shared__ unsigned short ps[64 * 128];     // [p][n]
  __shared__ float acs_s[128];
  int t = threadIdx.x, lane = t & 63, w = t >> 6, wr = w >> 1, wc = w & 1;
  int srow = t >> 4, scol = (t & 15) * 8;
  const unsigned short* Bg = xc + ((size_t)b * SEQ + c * 128) * DXBC + DINNER;
  const unsigned short* Cg = Bg + DSTATE;
#pragma unroll
  for (int s = 0; s < 8; ++s) {
    int r = s * 16 + srow;
    gload16(&Bg[(size_t)r * DXBC + scol], &Bs[r * 128 + scol]);
    gload16(&Cg[(size_t)r * DXBC + scol], &Cs[r * 128 + scol]);
  }
  const unsigned short* xg = xdtT + (((size_t)b * 64 + h) * 64) * SEQ + c * 128;
#pragma unroll
  for (int s = 0; s < 4; ++s) {
    int r = s * 16 + srow;
    gload16(&xg[(size_t)r * SEQ + scol], &xs[r * 128 + scol]);
  }
  const unsigned short* pg = prevb + ((((size_t)b * 16 + c) * 64 + h) * 64) * 128;
#pragma unroll
  for (int s = 0; s < 4; ++s) {
    int r = s * 16 + srow;
    gload16(&pg[r * 128 + scol], &ps[r * 128 + scol]);
  }
  const float* acsr = Acs + (((size_t)b * 64 + h) * 16 + c) * 128;
  if (t < 128) acs_s[t] = acsr[t];
  __syncthreads();

  // 1) CB^T: cbt -> D[m=j][n=i] = sum_n B[j,n] C[i,n]
  f32x4_t cbt[4][4];
#pragma unroll
  for (int i = 0; i < 4; ++i)
#pragma unroll
    for (int j = 0; j < 4; ++j) cbt[i][j] = (f32x4_t){0.f, 0.f, 0.f, 0.f};
#pragma unroll
  for (int ks = 0; ks < 4; ++ks) {
    const int kk = ks * 32 + (lane >> 4) * 8;
    u16x8_t af[4], bfr[4];
#pragma unroll
    for (int i = 0; i < 4; ++i) {
      af[i]  = *(const u16x8_t*)&Bs[(wr * 64 + i * 16 + (lane & 15)) * 128 + kk];
      bfr[i] = *(const u16x8_t*)&Cs[(wc * 64 + i * 16 + (lane & 15)) * 128 + kk];
    }
#pragma unroll
    for (int i = 0; i < 4; ++i)
#pragma unroll
      for (int j = 0; j < 4; ++j) cbt[i][j] = mfma16(af[i], bfr[j], cbt[i][j]);
  }
  __syncthreads();   // all waves done reading Bs before M overwrites it
  // build M[i][j] = (i>=j) ? CB * exp(acs[i]-acs[j]) : 0   (stored into Bs)
#pragma unroll
  for (int fi = 0; fi < 4; ++fi) {
#pragma unroll
    for (int fj = 0; fj < 4; ++fj) {
      int i = wc * 64 + fj * 16 + (lane & 15);
      int jb = wr * 64 + fi * 16 + (lane >> 4) * 4;
      float ai = acs_s[i];
      u16x4_t m4;
#pragma unroll
      for (int r = 0; r < 4; ++r) {
        int j = jb + r;
        float v = (i >= j) ? cbt[fi][fj][r] * __expf(ai - acs_s[j]) : 0.f;
        m4[r] = f2bf(v);
      }
      *(u16x4_t*)&Bs[i * 128 + jb] = m4;
    }
  }
  __syncthreads();

  // 2) Y_diag[i][p] = sum_j M[i,j] xdtT[p,j] ; 3) Y_off[i][p] = sum_n C[i,n] prev[p,n]
  f32x4_t accY[4][2], accO[4][2];
#pragma unroll
  for (int i = 0; i < 4; ++i)
#pragma unroll
    for (int j = 0; j < 2; ++j) {
      accY[i][j] = (f32x4_t){0.f, 0.f, 0.f, 0.f};
      accO[i][j] = (f32x4_t){0.f, 0.f, 0.f, 0.f};
    }
#pragma unroll
  for (int ks = 0; ks < 4; ++ks) {
    const int kk = ks * 32 + (lane >> 4) * 8;
    u16x8_t af[4], bfr[2], cf[4], pf[2];
#pragma unroll
    for (int i = 0; i < 4; ++i) {
      af[i] = *(const u16x8_t*)&Bs[(wr * 64 + i * 16 + (lane & 15)) * 128 + kk];
      cf[i] = *(const u16x8_t*)&Cs[(wr * 64 + i * 16 + (lane & 15)) * 128 + kk];
    }
#pragma unroll
    for (int j = 0; j < 2; ++j) {
      bfr[j] = *(const u16x8_t*)&xs[(wc * 32 + j * 16 + (lane & 15)) * 128 + kk];
      pf[j]  = *(const u16x8_t*)&ps[(wc * 32 + j * 16 + (lane & 15)) * 128 + kk];
    }
#pragma unroll
    for (int i = 0; i < 4; ++i)
#pragma unroll
      for (int j = 0; j < 2; ++j) {
        accY[i][j] = mfma16(af[i], bfr[j], accY[i][j]);
        accO[i][j] = mfma16(cf[i], pf[j], accO[i][j]);
      }
  }
  // epilogue
  float Dh = Dp[h];
  unsigned short* Yo = Y + ((size_t)b * SEQ + c * 128) * DINNER + h * 64;
  const unsigned short* xo = xc + ((size_t)b * SEQ + c * 128) * DXBC + h * 64;
#pragma unroll
  for (int fi = 0; fi < 4; ++fi) {
    int ibase = wr * 64 + fi * 16 + (lane >> 4) * 4;
#pragma unroll
    for (int r = 0; r < 4; ++r) {
      int i = ibase + r;
      float esc = __expf(acs_s[i]);
#pragma unroll
      for (int fj = 0; fj < 2; ++fj) {
        int p = wc * 32 + fj * 16 + (lane & 15);
        float v = accY[fi][fj][r] + accO[fi][fj][r] * esc + bf2f(xo[(size_t)i * DXBC + p]) * Dh;
        Yo[(size_t)i * DINNER + p] = f2bf(v);
      }
    }
  }
}

// ---------------- gated RMSNorm (bf16 Y) -> bf16 ----------------
__global__ __launch_bounds__(256) void norm_kernel(const unsigned short* __restrict__ Y,
                                                   const unsigned short* __restrict__ zx,
                                                   const float* __restrict__ nw,
                                                   unsigned short* __restrict__ yn) {
  int bl = blockIdx.x;
  const unsigned short* yr = Y + (size_t)bl * DINNER;
  const unsigned short* zr = zx + (size_t)bl * NPAD;
  int t = threadIdx.x;
  float vals[16];
  float ss = 0.f;
#pragma unroll
  for (int k = 0; k < 16; ++k) {
    int d = t + k * 256;
    float g = bf2f(yr[d]) * siluf(bf2f(zr[d]));
    vals[k] = g;
    ss += g * g;
  }
#pragma unroll
  for (int o = 32; o > 0; o >>= 1) ss += __shfl_down(ss, o, 64);
  __shared__ float red[4];
  if ((t & 63) == 0) red[t >> 6] = ss;
  __syncthreads();
  float tot = red[0] + red[1] + red[2] + red[3];
  float rs = rsqrtf(tot * (1.f / (float)DINNER) + 1e-5f);
#pragma unroll
  for (int k = 0; k < 16; ++k) {
    int d = t + k * 256;
    yn[(size_t)bl * DINNER + d] = f2bf(vals[k] * rs * nw[d]);
  }
}

// ---------------- host ----------------
extern "C" void kernel_launch(void* const* d_in, const int* in_sizes, int n_in,
                              void* d_out, int out_size, void* d_ws, size_t ws_size,
                              hipStream_t stream) {
  const float* u       = (const float*)d_in[0];
  const float* W_in    = (const float*)d_in[1];
  const float* conv_w  = (const float*)d_in[2];
  const float* conv_b  = (const float*)d_in[3];
  const float* dt_bias = (const float*)d_in[4];
  const float* A_log   = (const float*)d_in[5];
  const float* Dv      = (const float*)d_in[6];
  const float* norm_w  = (const float*)d_in[7];
  const float* W_out   = (const float*)d_in[8];
  float* out = (float*)d_out;
  (void)in_sizes; (void)n_in; (void)out_size;

  // ---- byte sizes ----
  const size_t SZ_UBF    = (size_t)BL * DMODEL * 2;
  const size_t SZ_WIN    = (size_t)NPAD * DMODEL * 2;
  const size_t SZ_XDTT   = (size_t)NBATCH * NHEADS * HEADDIM * SEQ * 2;
  const size_t SZ_ZX     = (size_t)BL * NPAD * 2;
  const size_t SZ_XC     = (size_t)BL * DXBC * 2;
  const size_t SZ_BT     = (size_t)NBATCH * DSTATE * SEQ * 2;
  const size_t SZ_DTS    = (size_t)NBATCH * NHEADS * SEQ * 4;
  const size_t SZ_ACS    = (size_t)NBATCH * NHEADS * NCHUNK * 128 * 4;
  const size_t SZ_CDEC   = (size_t)NBATCH * NHEADS * NCHUNK * 4;
  const size_t SZ_STATES = (size_t)NBATCH * NCHUNK * NHEADS * HEADDIM * DSTATE * 4; // f32; also holds Y bf16
  const size_t SZ_PREV   = (size_t)NBATCH * NCHUNK * NHEADS * HEADDIM * DSTATE * 2; // bf16; also holds yn
  const size_t REGION_A  = SZ_UBF + SZ_WIN;   // holds (u_bf,win_bf) then (xdtT,wout_bf)

  char* ws = (char*)d_ws;
  size_t off = 0;
  auto alloc = [&](size_t bytes) { char* p = ws + off; off += (bytes + 255) & ~(size_t)255; return p; };

  char* regionA = alloc(REGION_A);
  unsigned short* zx     = (unsigned short*)alloc(SZ_ZX);
  unsigned short* xc     = (unsigned short*)alloc(SZ_XC);
  unsigned short* BT     = (unsigned short*)alloc(SZ_BT);
  float* dt_soft         = (float*)alloc(SZ_DTS);
  float* Acs             = (float*)alloc(SZ_ACS);
  float* cdecay          = (float*)alloc(SZ_CDEC);
  char* statesYb         = alloc(SZ_STATES);
  char* prevYn           = alloc(SZ_PREV);
  if (off > ws_size) return;   // insufficient workspace: bail cleanly

  unsigned short* u_bf    = (unsigned short*)regionA;
  unsigned short* win_bf  = (unsigned short*)(regionA + SZ_UBF);
  unsigned short* xdtT    = (unsigned short*)regionA;
  unsigned short* wout_bf = (unsigned short*)(regionA + SZ_XDTT);
  float* states           = (float*)statesYb;
  unsigned short* Yb      = (unsigned short*)statesYb;   // bf16 Y after states dead
  unsigned short* prevb   = (unsigned short*)prevYn;
  unsigned short* yn      = (unsigned short*)prevYn;     // after prevb dead

  // phase 1 converts
  cvt_kernel<<<dim3((BL * DMODEL / 4 + 255) / 256), dim3(256), 0, stream>>>(u, u_bf, BL * DMODEL);
  cvt_win_kernel<<<dim3(NPAD * DMODEL / 4 / 256), dim3(256), 0, stream>>>(W_in, win_bf);

  // GEMM1: zx[BL][NPAD](bf16) = u_bf @ win_bf^T   (BM=256, 544 blocks, R4 schedule)
  gemm256_kernel<8, true, false><<<dim3((NPAD / 256) * (BL / 256)), dim3(512), 0, stream>>>(
      u_bf, win_bf, zx, BL, NPAD, DMODEL, NPAD / 256);

  // regionA now reusable: W_out convert
  cvt_kernel<<<dim3((DMODEL * DINNER / 4 + 255) / 256), dim3(256), 0, stream>>>(W_out, wout_bf, DMODEL * DINNER);

  // conv + silu (x, B, C all inside xc), 8 channels/thread
  conv_kernel<<<dim3(BL * (DXBC / 8) / 256), dim3(256), 0, stream>>>(zx, conv_w, conv_b, xc);

  // dt softplus + cumsum
  dt_kernel<<<dim3(NBATCH * NHEADS * NCHUNK), dim3(128), 0, stream>>>(zx, dt_bias, A_log, dt_soft, Acs, cdecay);

  // xdt^T and B^T
  xdt_kernel<<<dim3(NBATCH * NHEADS * NCHUNK), dim3(256), 0, stream>>>(xc, dt_soft, xdtT);
  btr_kernel<<<dim3(NBATCH * (SEQ / 128)), dim3(256), 0, stream>>>(xc, BT);

  // SSD
  ssd_states_kernel<<<dim3(NBATCH * NCHUNK * NHEADS), dim3(256), 0, stream>>>(BT, xdtT, Acs, states);
  ssd_scan_kernel<<<dim3(NBATCH * NHEADS * 8), dim3(256), 0, stream>>>(states, cdecay, prevb);
  ssd_y_kernel<<<dim3(NBATCH * NCHUNK * NHEADS), dim3(256), 0, stream>>>(xc, xdtT, prevb, Acs, Dv, Yb);

  // gated RMSNorm (Yb bf16 -> yn; yn aliases prevb which is dead now)
  norm_kernel<<<dim3(BL), dim3(256), 0, stream>>>(Yb, zx, norm_w, yn);

  // GEMM2: out[BL][DMODEL](f32) = yn @ wout_bf^T   (BM=128, 256 blocks, fine schedule)
  gemm256_kernel<4, false, true><<<dim3((DMODEL / 256) * (BL / 128)), dim3(512), 0, stream>>>(
      yn, wout_bf, out, BL, DMODEL, DINNER, DMODEL / 256);
}

// Round 9
// 560.321 us; speedup vs baseline: 1.0731x; 1.0731x over previous
//
#include <hip/hip_runtime.h>
#include <cstdint>
#include <cstddef>

#define SEQ     2048
#define NBATCH  2
#define BL      (NBATCH*SEQ)     // 4096
#define DMODEL  2048
#define DINNER  4096
#define DSTATE  128
#define HEADDIM 64
#define NHEADS  64
#define DXBC    4352
#define DPROJ   8512
#define NPAD    8704             // padded D_IN_PROJ (34*256)
#define NCHUNK  16
#define CHUNKL  128

typedef __bf16 bf16x8_t __attribute__((ext_vector_type(8)));
typedef float f32x4_t __attribute__((ext_vector_type(4)));
typedef unsigned short u16x8_t __attribute__((ext_vector_type(8)));
typedef unsigned short u16x4_t __attribute__((ext_vector_type(4)));
typedef __attribute__((address_space(1))) unsigned int as1_u32;
typedef __attribute__((address_space(3))) unsigned int as3_u32;

__device__ __forceinline__ unsigned short f2bf(float f) {
  unsigned u = __builtin_bit_cast(unsigned, f);
  u += 0x7FFFu + ((u >> 16) & 1u);
  return (unsigned short)(u >> 16);
}
__device__ __forceinline__ float bf2f(unsigned short h) {
  unsigned u = ((unsigned)h) << 16;
  return __builtin_bit_cast(float, u);
}
__device__ __forceinline__ void gload16(const void* g, void* l) {
  __builtin_amdgcn_global_load_lds((const as1_u32*)g, (as3_u32*)l, 16, 0, 0);
}
__device__ __forceinline__ f32x4_t mfma16(u16x8_t a, u16x8_t b, f32x4_t c) {
  return __builtin_amdgcn_mfma_f32_16x16x32_bf16(
      __builtin_bit_cast(bf16x8_t, a), __builtin_bit_cast(bf16x8_t, b), c, 0, 0, 0);
}
__device__ __forceinline__ float siluf(float x) { return x / (1.f + __expf(-x)); }

// ---------------- converts ----------------
__global__ __launch_bounds__(256) void cvt_kernel(const float* __restrict__ src,
                                                  unsigned short* __restrict__ dst, int n) {
  int idx = (blockIdx.x * 256 + threadIdx.x) * 4;
  if (idx >= n) return;
  float4 v = *(const float4*)&src[idx];
  u16x4_t o; o[0] = f2bf(v.x); o[1] = f2bf(v.y); o[2] = f2bf(v.z); o[3] = f2bf(v.w);
  *(u16x4_t*)&dst[idx] = o;
}

__global__ __launch_bounds__(256) void cvt_win_kernel(const float* __restrict__ W,
                                                      unsigned short* __restrict__ dst) {
  int idx = (blockIdx.x * 256 + threadIdx.x) * 4;
  if (idx >= NPAD * DMODEL) return;
  int e = idx / DMODEL;
  u16x4_t o;
  if (e < DPROJ) {
    float4 v = *(const float4*)&W[idx];
    o[0] = f2bf(v.x); o[1] = f2bf(v.y); o[2] = f2bf(v.z); o[3] = f2bf(v.w);
  } else {
    o[0] = 0; o[1] = 0; o[2] = 0; o[3] = 0;
  }
  *(u16x4_t*)&dst[idx] = o;
}

// ---------------- GEMM: C[M][N] = A[M][K] * B[N][K]^T, bf16 in ----------------
// R4-measured-best schedule (179 us, MfmaUtil 35%, 0 bank conflicts):
// BM = 32*WM (GEMM1: 256, GEMM2: 128), BN = 256, BK = 32, 8 waves (2M x 4N),
// 4-buffer LDS ring, counted vmcnt (2 tiles in flight, never 0 mid-loop),
// XOR swizzle for 64B rows, one barrier per K-tile.
template <int WM, bool BF16OUT>
__global__ __launch_bounds__(512, 2) void gemm256_kernel(const unsigned short* __restrict__ A,
                                                         const unsigned short* __restrict__ B,
                                                         void* __restrict__ Cp,
                                                         int M, int N, int K, int gx) {
  constexpr int BM  = 32 * WM;
  constexpr int AUB = BM * 64;          // A-unit bytes per K-tile
  constexpr int BUB = 16384;            // B-unit bytes (256 rows x 64B)
  constexpr int BUF = AUB + BUB;
  constexpr int LA  = AUB / 8192;       // gload instrs per thread, A unit
  constexpr int LB  = 2;
  constexpr int LT  = LA + LB;          // loads per tile
  __shared__ __attribute__((aligned(16))) char lds[4 * BUF];

  const int nwg = gridDim.x;
  const int q8 = nwg >> 3;
  const int lid = blockIdx.x;
  const int newid = (lid & 7) * q8 + (lid >> 3);     // bijective XCD chunking
  const int band = newid / (gx * 4);
  const int idx  = newid % (gx * 4);
  const int n0 = (idx >> 2) * 256;
  const int m0 = (band * 4 + (idx & 3)) * BM;

  const int t = threadIdx.x, lane = t & 63, w = t >> 6;
  const int wm = w >> 2, wn = w & 3;                 // 2 x 4 waves
  const int NK = K >> 5;
  const int kslot = (lane >> 4) * 16;                // 16B col-slot

  f32x4_t acc[WM][4];
#pragma unroll
  for (int i = 0; i < WM; ++i)
#pragma unroll
    for (int j = 0; j < 4; ++j) acc[i][j] = (f32x4_t){0.f, 0.f, 0.f, 0.f};

  auto stage_unit = [&](int u) {
    if (u >= 2 * NK) return;
    const int Tt = u >> 1;
    char* base = lds + (Tt & 3) * BUF + ((u & 1) ? AUB : 0);
    const unsigned short* G = (u & 1) ? B : A;
    const int g0 = (u & 1) ? n0 : m0;
    const int k0 = Tt << 5;
    if (u & 1) {
#pragma unroll
      for (int i = 0; i < LB; ++i) {
        int o = i * 8192 + t * 16;
        int row = o >> 6;
        int cb = (o & 63) ^ (((row >> 1) & 3) << 4);     // inverse-swizzle source
        gload16(&G[(size_t)(g0 + row) * K + k0 + (cb >> 1)], base + o);
      }
    } else {
#pragma unroll
      for (int i = 0; i < LA; ++i) {
        int o = i * 8192 + t * 16;
        int row = o >> 6;
        int cb = (o & 63) ^ (((row >> 1) & 3) << 4);
        gload16(&G[(size_t)(g0 + row) * K + k0 + (cb >> 1)], base + o);
      }
    }
  };
  auto rdA = [&](int bq, int mr) -> u16x8_t {
    int row = wm * (BM / 2) + mr * 16 + (lane & 15);
    int byte = bq * BUF + row * 64 + (kslot ^ (((row >> 1) & 3) << 4));
    return *(const u16x8_t*)(lds + byte);
  };
  auto rdB = [&](int bq, int nr) -> u16x8_t {
    int row = wn * 64 + nr * 16 + (lane & 15);
    int byte = bq * BUF + AUB + row * 64 + (kslot ^ (((row >> 1) & 3) << 4));
    return *(const u16x8_t*)(lds + byte);
  };

  // prologue: tiles 0,1,2 in flight (3*LT loads)
#pragma unroll
  for (int u = 0; u < 6; ++u) stage_unit(u);

  for (int T = 0; T < NK; ++T) {
    const int bq = T & 3;
    if (T <= NK - 3)      { if constexpr (LT == 4) asm volatile("s_waitcnt vmcnt(8)" ::: "memory");
                            else                   asm volatile("s_waitcnt vmcnt(6)" ::: "memory"); }
    else if (T == NK - 2) { if constexpr (LT == 4) asm volatile("s_waitcnt vmcnt(4)" ::: "memory");
                            else                   asm volatile("s_waitcnt vmcnt(3)" ::: "memory"); }
    else                  asm volatile("s_waitcnt vmcnt(0)" ::: "memory");
    __builtin_amdgcn_s_barrier();
    asm volatile("" ::: "memory");
    __builtin_amdgcn_sched_barrier(0);

    u16x8_t af[WM], bfr[4];
    // phase 0: read A-frags + B 0,1; stage next A-unit; MFMA nr 0,1
#pragma unroll
    for (int mr = 0; mr < WM; ++mr) af[mr] = rdA(bq, mr);
    bfr[0] = rdB(bq, 0);
    bfr[1] = rdB(bq, 1);
    stage_unit(2 * T + 6);
    __builtin_amdgcn_s_setprio(1);
#pragma unroll
    for (int mr = 0; mr < WM; ++mr) {
      acc[mr][0] = mfma16(af[mr], bfr[0], acc[mr][0]);
      acc[mr][1] = mfma16(af[mr], bfr[1], acc[mr][1]);
    }
    __builtin_amdgcn_s_setprio(0);
    // phase 1: read B 2,3; stage next B-unit; MFMA nr 2,3
    bfr[2] = rdB(bq, 2);
    bfr[3] = rdB(bq, 3);
    stage_unit(2 * T + 7);
    __builtin_amdgcn_s_setprio(1);
#pragma unroll
    for (int mr = 0; mr < WM; ++mr) {
      acc[mr][2] = mfma16(af[mr], bfr[2], acc[mr][2]);
      acc[mr][3] = mfma16(af[mr], bfr[3], acc[mr][3]);
    }
    __builtin_amdgcn_s_setprio(0);
  }

  // epilogue
#pragma unroll
  for (int mr = 0; mr < WM; ++mr) {
    const int mbase = m0 + wm * (BM / 2) + mr * 16 + (lane >> 4) * 4;
#pragma unroll
    for (int nr = 0; nr < 4; ++nr) {
      const int n = n0 + wn * 64 + nr * 16 + (lane & 15);
#pragma unroll
      for (int r = 0; r < 4; ++r) {
        if (BF16OUT) ((unsigned short*)Cp)[(size_t)(mbase + r) * N + n] = f2bf(acc[mr][nr][r]);
        else         ((float*)Cp)[(size_t)(mbase + r) * N + n] = acc[mr][nr][r];
      }
    }
  }
}

// -------- depthwise causal conv + silu, 8 channels/thread (bf16 vec) --------
__global__ __launch_bounds__(256) void conv_kernel(const unsigned short* __restrict__ zx,
                                                   const float* __restrict__ conv_w,
                                                   const float* __restrict__ conv_b,
                                                   unsigned short* __restrict__ xc) {
  int idx = blockIdx.x * 256 + threadIdx.x;
  if (idx >= BL * (DXBC / 8)) return;
  int e8 = (idx % (DXBC / 8)) * 8;
  int bl = idx / (DXBC / 8);
  int l = bl % SEQ, b = bl / SEQ;
  float acc[8];
#pragma unroll
  for (int j = 0; j < 8; ++j) acc[j] = conv_b[e8 + j];
  const unsigned short* zrow = zx + (size_t)b * SEQ * NPAD + DINNER + e8;
#pragma unroll
  for (int wi = 0; wi < 4; ++wi) {
    int ll = l - 3 + wi;
    if (ll >= 0) {
      u16x8_t v = *(const u16x8_t*)(zrow + (size_t)ll * NPAD);
#pragma unroll
      for (int j = 0; j < 8; ++j) acc[j] += bf2f(v[j]) * conv_w[(e8 + j) * 4 + wi];
    }
  }
  u16x8_t o;
#pragma unroll
  for (int j = 0; j < 8; ++j) o[j] = f2bf(siluf(acc[j]));
  *(u16x8_t*)(xc + (size_t)bl * DXBC + e8) = o;
}

// ---------------- dt softplus + per-chunk cumsum of dA ----------------
__global__ __launch_bounds__(128) void dt_kernel(const unsigned short* __restrict__ zx,
                                                 const float* __restrict__ dt_bias,
                                                 const float* __restrict__ A_log,
                                                 float* __restrict__ dt_soft,   // [b][h][l]
                                                 float* __restrict__ Acs,       // [b][h][c][128]
                                                 float* __restrict__ cdecay) {  // [b][h][c]
  int blk = blockIdx.x;                       // (b*64+h)*16+c
  int c = blk & 15, h = (blk >> 4) & 63, b = blk >> 10;
  int i = threadIdx.x;
  int l = c * CHUNKL + i;
  float raw = bf2f(zx[((size_t)b * SEQ + l) * NPAD + (DINNER + DXBC) + h]) + dt_bias[h];
  float dt = (raw > 20.f) ? raw : log1pf(__expf(raw));
  dt_soft[((size_t)b * 64 + h) * SEQ + l] = dt;
  float A = -__expf(A_log[h]);
  __shared__ float sbuf[128];
  sbuf[i] = dt * A;
  __syncthreads();
  for (int ofs = 1; ofs < 128; ofs <<= 1) {
    float v = (i >= ofs) ? sbuf[i - ofs] : 0.f;
    __syncthreads();
    sbuf[i] += v;
    __syncthreads();
  }
  float cs = sbuf[i];
  Acs[(((size_t)b * 64 + h) * 16 + c) * 128 + i] = cs;
  if (i == 127) cdecay[((size_t)b * 64 + h) * 16 + c] = __expf(cs);
}

// ---------------- xdt^T builder: xdtT[b][h][p][l] = x[b,l,h*64+p]*dt ----------
__global__ __launch_bounds__(256) void xdt_kernel(const unsigned short* __restrict__ xc,
                                                  const float* __restrict__ dt_soft,
                                                  unsigned short* __restrict__ xdtT) {
  int blk = blockIdx.x;                       // (b*64+h)*16+lt
  int lt = blk & 15, h = (blk >> 4) & 63, b = blk >> 10;
  __shared__ unsigned short tile[128][66];
  __shared__ float dts[128];
  int t = threadIdx.x;
  const unsigned short* xg = xc + ((size_t)b * SEQ + lt * 128) * DXBC + h * 64;
#pragma unroll
  for (int k = 0; k < 32; ++k) {
    int idx = t + k * 256;
    int row = idx >> 6, col = idx & 63;
    tile[row][col] = xg[(size_t)row * DXBC + col];
  }
  if (t < 128) dts[t] = dt_soft[((size_t)b * 64 + h) * SEQ + lt * 128 + t];
  __syncthreads();
  unsigned short* xo = xdtT + (((size_t)b * 64 + h) * 64) * SEQ + lt * 128;
#pragma unroll
  for (int k = 0; k < 32; ++k) {
    int idx = t + k * 256;
    int p = idx >> 7, j = idx & 127;
    xo[(size_t)p * SEQ + j] = f2bf(bf2f(tile[j][p]) * dts[j]);
  }
}

// ---------------- B transpose from xc: BT[b][n][l] ----------------
__global__ __launch_bounds__(256) void btr_kernel(const unsigned short* __restrict__ xc,
                                                  unsigned short* __restrict__ BT) {
  int blk = blockIdx.x;                       // b*16+lt
  int lt = blk & 15, b = blk >> 4;
  __shared__ unsigned short tile[128][129];
  int t = threadIdx.x;
  const unsigned short* src = xc + ((size_t)b * SEQ + lt * 128) * DXBC + DINNER;
#pragma unroll
  for (int k = 0; k < 64; ++k) {
    int idx = t + k * 256;
    int j = idx >> 7, n = idx & 127;
    tile[j][n] = src[(size_t)j * DXBC + n];
  }
  __syncthreads();
  unsigned short* dst = BT + (size_t)b * 128 * SEQ + lt * 128;
#pragma unroll
  for (int k = 0; k < 64; ++k) {
    int idx = t + k * 256;
    int n = idx >> 7, j = idx & 127;
    dst[(size_t)n * SEQ + j] = tile[j][n];
  }
}

// -------- SSD per-chunk states (bf16 out): states[b][c][h][p][n] --------
__global__ __launch_bounds__(256) void ssd_states_kernel(const unsigned short* __restrict__ BT,
                                                         const unsigned short* __restrict__ xdtT,
                                                         const float* __restrict__ Acs,
                                                         unsigned short* __restrict__ states) {
  int blk = blockIdx.x;                       // ((b*16+c)*64+h)
  int h = blk & 63, c = (blk >> 6) & 15, b = blk >> 10;
  __shared__ unsigned short BTs[128 * 128];   // [n][j]
  __shared__ unsigned short xs[64 * 128];     // [p][j]
  __shared__ float dec[128];
  int t = threadIdx.x, lane = t & 63, w = t >> 6, wr = w >> 1, wc = w & 1;
  int srow = t >> 4, scol = (t & 15) * 8;
  const unsigned short* BTb = BT + (size_t)b * 128 * SEQ + c * 128;
#pragma unroll
  for (int s = 0; s < 8; ++s) {
    int r = s * 16 + srow;
    gload16(&BTb[(size_t)r * SEQ + scol], &BTs[r * 128 + scol]);
  }
  const unsigned short* xb = xdtT + (((size_t)b * 64 + h) * 64) * SEQ + c * 128;
#pragma unroll
  for (int s = 0; s < 4; ++s) {
    int r = s * 16 + srow;
    gload16(&xb[(size_t)r * SEQ + scol], &xs[r * 128 + scol]);
  }
  const float* acsr = Acs + (((size_t)b * 64 + h) * 16 + c) * 128;
  float alast = acsr[127];
  if (t < 128) dec[t] = __expf(alast - acsr[t]);
  __syncthreads();

  f32x4_t acc[2][4];
#pragma unroll
  for (int i = 0; i < 2; ++i)
#pragma unroll
    for (int j = 0; j < 4; ++j) acc[i][j] = (f32x4_t){0.f, 0.f, 0.f, 0.f};
#pragma unroll
  for (int ks = 0; ks < 4; ++ks) {
    const int kk = ks * 32 + (lane >> 4) * 8;
    float d8[8];
#pragma unroll
    for (int e = 0; e < 8; ++e) d8[e] = dec[kk + e];
    u16x8_t af[2], bfr[4];
#pragma unroll
    for (int i = 0; i < 2; ++i) {
      u16x8_t raw = *(const u16x8_t*)&xs[(wr * 32 + i * 16 + (lane & 15)) * 128 + kk];
      u16x8_t sc;
#pragma unroll
      for (int e = 0; e < 8; ++e) sc[e] = f2bf(bf2f(raw[e]) * d8[e]);
      af[i] = sc;
    }
#pragma unroll
    for (int j = 0; j < 4; ++j)
      bfr[j] = *(const u16x8_t*)&BTs[(wc * 64 + j * 16 + (lane & 15)) * 128 + kk];
#pragma unroll
    for (int i = 0; i < 2; ++i)
#pragma unroll
      for (int j = 0; j < 4; ++j) acc[i][j] = mfma16(af[i], bfr[j], acc[i][j]);
  }
  unsigned short* so = states + ((((size_t)b * 16 + c) * 64 + h) * 64) * 128;
#pragma unroll
  for (int i = 0; i < 2; ++i) {
    int pbase = wr * 32 + i * 16 + (lane >> 4) * 4;
#pragma unroll
    for (int j = 0; j < 4; ++j) {
      int n = wc * 64 + j * 16 + (lane & 15);
#pragma unroll
      for (int r = 0; r < 4; ++r) so[(size_t)(pbase + r) * 128 + n] = f2bf(acc[i][j][r]);
    }
  }
}

// ------ inter-chunk scan: all 16 chunk loads upfront (one latency), vec u16x4 ------
__global__ __launch_bounds__(256) void ssd_scan_kernel(const unsigned short* __restrict__ states,
                                                       const float* __restrict__ cdecay,
                                                       unsigned short* __restrict__ prevb) {
  int blk = blockIdx.x;                       // ((b*64+h)*8 + s)
  int s = blk & 7, h = (blk >> 3) & 63, b = blk >> 9;
  int t = threadIdx.x;
  const size_t eoff = (size_t)s * 1024 + t * 4;     // 4 consecutive elems/thread
  const float* cd = cdecay + ((size_t)b * 64 + h) * 16;
  u16x4_t vals[16];
#pragma unroll
  for (int c = 0; c < 16; ++c) {
    const unsigned short* sp = states + (((size_t)(b * 16 + c) * 64 + h) * 64) * 128 + eoff;
    vals[c] = *(const u16x4_t*)sp;               // independent; all issued upfront
  }
  float carry[4] = {0.f, 0.f, 0.f, 0.f};
#pragma unroll
  for (int c = 0; c < 16; ++c) {
    unsigned short* pp = prevb + (((size_t)(b * 16 + c) * 64 + h) * 64) * 128 + eoff;
    u16x4_t o;
#pragma unroll
    for (int k = 0; k < 4; ++k) o[k] = f2bf(carry[k]);
    *(u16x4_t*)pp = o;
    float d = cd[c];
#pragma unroll
    for (int k = 0; k < 4; ++k) carry[k] = carry[k] * d + bf2f(vals[c][k]);
  }
}

// ---------------- SSD Y = Y_diag + Y_off + D*x (bf16 out) ----------------
// LDS = Bs+Cs+xs = exactly 80 KB -> 2 blocks/CU. prev fragments prefetched
// direct global->register (identity layout); acs read from L1-hot global.
__global__ __launch_bounds__(256) void ssd_y_kernel(const unsigned short* __restrict__ xc,
                                                    const unsigned short* __restrict__ xdtT,
                                                    const unsigned short* __restrict__ prevb,
                                                    const float* __restrict__ Acs,
                                                    const float* __restrict__ Dp,
                                                    unsigned short* __restrict__ Y) {
  int blk = blockIdx.x;                       // ((b*16+c)*64+h)
  int h = blk & 63, c = (blk >> 6) & 15, b = blk >> 10;
  __shared__ unsigned short Bs[128 * 128];    // [j][n], reused as M[i][j]
  __shared__ unsigned short Cs[128 * 128];    // [i][n]
  __shared__ unsigned short xs[64 * 128];     // [p][j]
  int t = threadIdx.x, lane = t & 63, w = t >> 6, wr = w >> 1, wc = w & 1;
  int srow = t >> 4, scol = (t & 15) * 8;
  const unsigned short* Bg = xc + ((size_t)b * SEQ + c * 128) * DXBC + DINNER;
  const unsigned short* Cg = Bg + DSTATE;
#pragma unroll
  for (int s = 0; s < 8; ++s) {
    int r = s * 16 + srow;
    gload16(&Bg[(size_t)r * DXBC + scol], &Bs[r * 128 + scol]);
    gload16(&Cg[(size_t)r * DXBC + scol], &Cs[r * 128 + scol]);
  }
  const unsigned short* xg = xdtT + (((size_t)b * 64 + h) * 64) * SEQ + c * 128;
#pragma unroll
  for (int s = 0; s < 4; ++s) {
    int r = s * 16 + srow;
    gload16(&xg[(size_t)r * SEQ + scol], &xs[r * 128 + scol]);
  }
  // prefetch prev fragments straight to registers (same indices the old LDS path used)
  const unsigned short* pg = prevb + ((((size_t)b * 16 + c) * 64 + h) * 64) * 128;
  u16x8_t pf_all[4][2];
#pragma unroll
  for (int ks = 0; ks < 4; ++ks) {
    const int kk = ks * 32 + (lane >> 4) * 8;
#pragma unroll
    for (int j = 0; j < 2; ++j)
      pf_all[ks][j] = *(const u16x8_t*)&pg[(size_t)(wc * 32 + j * 16 + (lane & 15)) * 128 + kk];
  }
  const float* acsr = Acs + (((size_t)b * 64 + h) * 16 + c) * 128;
  __syncthreads();

  // 1) CB^T: cbt -> D[m=j][n=i] = sum_n B[j,n] C[i,n]
  f32x4_t cbt[4][4];
#pragma unroll
  for (int i = 0; i < 4; ++i)
#pragma unroll
    for (int j = 0; j < 4; ++j) cbt[i][j] = (f32x4_t){0.f, 0.f, 0.f, 0.f};
#pragma unroll
  for (int ks = 0; ks < 4; ++ks) {
    const int kk = ks * 32 + (lane >> 4) * 8;
    u16x8_t af[4], bfr[4];
#pragma unroll
    for (int i = 0; i < 4; ++i) {
      af[i]  = *(const u16x8_t*)&Bs[(wr * 64 + i * 16 + (lane & 15)) * 128 + kk];
      bfr[i] = *(const u16x8_t*)&Cs[(wc * 64 + i * 16 + (lane & 15)) * 128 + kk];
    }
#pragma unroll
    for (int i = 0; i < 4; ++i)
#pragma unroll
      for (int j = 0; j < 4; ++j) cbt[i][j] = mfma16(af[i], bfr[j], cbt[i][j]);
  }
  __syncthreads();   // all waves done reading Bs before M overwrites it
  // build M[i][j] = (i>=j) ? CB * exp(acs[i]-acs[j]) : 0   (stored into Bs)
#pragma unroll
  for (int fi = 0; fi < 4; ++fi) {
#pragma unroll
    for (int fj = 0; fj < 4; ++fj) {
      int i = wc * 64 + fj * 16 + (lane & 15);
      int jb = wr * 64 + fi * 16 + (lane >> 4) * 4;
      float ai = acsr[i];
      u16x4_t m4;
#pragma unroll
      for (int r = 0; r < 4; ++r) {
        int j = jb + r;
        float v = (i >= j) ? cbt[fi][fj][r] * __expf(ai - acsr[j]) : 0.f;
        m4[r] = f2bf(v);
      }
      *(u16x4_t*)&Bs[i * 128 + jb] = m4;
    }
  }
  __syncthreads();

  // 2) Y_diag[i][p] = sum_j M[i,j] xdtT[p,j] ; 3) Y_off[i][p] = sum_n C[i,n] prev[p,n]
  f32x4_t accY[4][2], accO[4][2];
#pragma unroll
  for (int i = 0; i < 4; ++i)
#pragma unroll
    for (int j = 0; j < 2; ++j) {
      accY[i][j] = (f32x4_t){0.f, 0.f, 0.f, 0.f};
      accO[i][j] = (f32x4_t){0.f, 0.f, 0.f, 0.f};
    }
#pragma unroll
  for (int ks = 0; ks < 4; ++ks) {
    const int kk = ks * 32 + (lane >> 4) * 8;
    u16x8_t af[4], bfr[2], cf[4];
#pragma unroll
    for (int i = 0; i < 4; ++i) {
      af[i] = *(const u16x8_t*)&Bs[(wr * 64 + i * 16 + (lane & 15)) * 128 + kk];
      cf[i] = *(const u16x8_t*)&Cs[(wr * 64 + i * 16 + (lane & 15)) * 128 + kk];
    }
#pragma unroll
    for (int j = 0; j < 2; ++j)
      bfr[j] = *(const u16x8_t*)&xs[(wc * 32 + j * 16 + (lane & 15)) * 128 + kk];
#pragma unroll
    for (int i = 0; i < 4; ++i)
#pragma unroll
      for (int j = 0; j < 2; ++j) {
        accY[i][j] = mfma16(af[i], bfr[j], accY[i][j]);
        accO[i][j] = mfma16(cf[i], pf_all[ks][j], accO[i][j]);
      }
  }
  // epilogue
  float Dh = Dp[h];
  unsigned short* Yo = Y + ((size_t)b * SEQ + c * 128) * DINNER + h * 64;
  const unsigned short* xo = xc + ((size_t)b * SEQ + c * 128) * DXBC + h * 64;
#pragma unroll
  for (int fi = 0; fi < 4; ++fi) {
    int ibase = wr * 64 + fi * 16 + (lane >> 4) * 4;
#pragma unroll
    for (int r = 0; r < 4; ++r) {
      int i = ibase + r;
      float esc = __expf(acsr[i]);
#pragma unroll
      for (int fj = 0; fj < 2; ++fj) {
        int p = wc * 32 + fj * 16 + (lane & 15);
        float v = accY[fi][fj][r] + accO[fi][fj][r] * esc + bf2f(xo[(size_t)i * DXBC + p]) * Dh;
        Yo[(size_t)i * DINNER + p] = f2bf(v);
      }
    }
  }
}

// ---------------- gated RMSNorm (bf16 Y) -> bf16, u16x8 vectorized ----------------
__global__ __launch_bounds__(256) void norm_kernel(const unsigned short* __restrict__ Y,
                                                   const unsigned short* __restrict__ zx,
                                                   const float* __restrict__ nw,
                                                   unsigned short* __restrict__ yn) {
  int bl = blockIdx.x;
  const unsigned short* yr = Y + (size_t)bl * DINNER;
  const unsigned short* zr = zx + (size_t)bl * NPAD;
  int t = threadIdx.x;
  int base = t * 16;                       // 16 consecutive elems/thread
  u16x8_t y0 = *(const u16x8_t*)&yr[base], y1 = *(const u16x8_t*)&yr[base + 8];
  u16x8_t z0 = *(const u16x8_t*)&zr[base], z1 = *(const u16x8_t*)&zr[base + 8];
  float vals[16];
  float ss = 0.f;
#pragma unroll
  for (int k = 0; k < 8; ++k) {
    float g = bf2f(y0[k]) * siluf(bf2f(z0[k]));
    vals[k] = g; ss += g * g;
  }
#pragma unroll
  for (int k = 0; k < 8; ++k) {
    float g = bf2f(y1[k]) * siluf(bf2f(z1[k]));
    vals[8 + k] = g; ss += g * g;
  }
#pragma unroll
  for (int o = 32; o > 0; o >>= 1) ss += __shfl_down(ss, o, 64);
  __shared__ float red[4];
  if ((t & 63) == 0) red[t >> 6] = ss;
  __syncthreads();
  float tot = red[0] + red[1] + red[2] + red[3];
  float rs = rsqrtf(tot * (1.f / (float)DINNER) + 1e-5f);
  u16x8_t o0, o1;
#pragma unroll
  for (int k = 0; k < 8; ++k) {
    o0[k] = f2bf(vals[k] * rs * nw[base + k]);
    o1[k] = f2bf(vals[8 + k] * rs * nw[base + 8 + k]);
  }
  *(u16x8_t*)&yn[(size_t)bl * DINNER + base] = o0;
  *(u16x8_t*)&yn[(size_t)bl * DINNER + base + 8] = o1;
}

// ---------------- host ----------------
extern "C" void kernel_launch(void* const* d_in, const int* in_sizes, int n_in,
                              void* d_out, int out_size, void* d_ws, size_t ws_size,
                              hipStream_t stream) {
  const float* u       = (const float*)d_in[0];
  const float* W_in    = (const float*)d_in[1];
  const float* conv_w  = (const float*)d_in[2];
  const float* conv_b  = (const float*)d_in[3];
  const float* dt_bias = (const float*)d_in[4];
  const float* A_log   = (const float*)d_in[5];
  const float* Dv      = (const float*)d_in[6];
  const float* norm_w  = (const float*)d_in[7];
  const float* W_out   = (const float*)d_in[8];
  float* out = (float*)d_out;
  (void)in_sizes; (void)n_in; (void)out_size;

  // ---- byte sizes ----
  const size_t SZ_UBF    = (size_t)BL * DMODEL * 2;
  const size_t SZ_WIN    = (size_t)NPAD * DMODEL * 2;
  const size_t SZ_XDTT   = (size_t)NBATCH * NHEADS * HEADDIM * SEQ * 2;
  const size_t SZ_ZX     = (size_t)BL * NPAD * 2;
  const size_t SZ_XC     = (size_t)BL * DXBC * 2;
  const size_t SZ_BT     = (size_t)NBATCH * DSTATE * SEQ * 2;
  const size_t SZ_DTS    = (size_t)NBATCH * NHEADS * SEQ * 4;
  const size_t SZ_ACS    = (size_t)NBATCH * NHEADS * NCHUNK * 128 * 4;
  const size_t SZ_CDEC   = (size_t)NBATCH * NHEADS * NCHUNK * 4;
  const size_t SZ_STATES = (size_t)NBATCH * NCHUNK * NHEADS * HEADDIM * DSTATE * 2; // bf16; also holds Y bf16
  const size_t SZ_PREV   = (size_t)NBATCH * NCHUNK * NHEADS * HEADDIM * DSTATE * 2; // bf16; also holds yn
  const size_t REGION_A  = SZ_UBF + SZ_WIN;   // holds (u_bf,win_bf) then (xdtT,wout_bf)

  char* ws = (char*)d_ws;
  size_t off = 0;
  auto alloc = [&](size_t bytes) { char* p = ws + off; off += (bytes + 255) & ~(size_t)255; return p; };

  char* regionA = alloc(REGION_A);
  unsigned short* zx     = (unsigned short*)alloc(SZ_ZX);
  unsigned short* xc     = (unsigned short*)alloc(SZ_XC);
  unsigned short* BT     = (unsigned short*)alloc(SZ_BT);
  float* dt_soft         = (float*)alloc(SZ_DTS);
  float* Acs             = (float*)alloc(SZ_ACS);
  float* cdecay          = (float*)alloc(SZ_CDEC);
  char* statesYb         = alloc(SZ_STATES);
  char* prevYn           = alloc(SZ_PREV);
  if (off > ws_size) return;   // insufficient workspace: bail cleanly

  unsigned short* u_bf    = (unsigned short*)regionA;
  unsigned short* win_bf  = (unsigned short*)(regionA + SZ_UBF);
  unsigned short* xdtT    = (unsigned short*)regionA;
  unsigned short* wout_bf = (unsigned short*)(regionA + SZ_XDTT);
  unsigned short* states  = (unsigned short*)statesYb;
  unsigned short* Yb      = (unsigned short*)statesYb;   // bf16 Y after states dead
  unsigned short* prevb   = (unsigned short*)prevYn;
  unsigned short* yn      = (unsigned short*)prevYn;     // after prevb dead

  // phase 1 converts
  cvt_kernel<<<dim3((BL * DMODEL / 4 + 255) / 256), dim3(256), 0, stream>>>(u, u_bf, BL * DMODEL);
  cvt_win_kernel<<<dim3(NPAD * DMODEL / 4 / 256), dim3(256), 0, stream>>>(W_in, win_bf);

  // GEMM1: zx[BL][NPAD](bf16) = u_bf @ win_bf^T   (BM=256, 544 blocks, R4 schedule)
  gemm256_kernel<8, true><<<dim3((NPAD / 256) * (BL / 256)), dim3(512), 0, stream>>>(
      u_bf, win_bf, zx, BL, NPAD, DMODEL, NPAD / 256);

  // regionA now reusable: W_out convert
  cvt_kernel<<<dim3((DMODEL * DINNER / 4 + 255) / 256), dim3(256), 0, stream>>>(W_out, wout_bf, DMODEL * DINNER);

  // conv + silu (x, B, C all inside xc), 8 channels/thread
  conv_kernel<<<dim3(BL * (DXBC / 8) / 256), dim3(256), 0, stream>>>(zx, conv_w, conv_b, xc);

  // dt softplus + cumsum
  dt_kernel<<<dim3(NBATCH * NHEADS * NCHUNK), dim3(128), 0, stream>>>(zx, dt_bias, A_log, dt_soft, Acs, cdecay);

  // xdt^T and B^T
  xdt_kernel<<<dim3(NBATCH * NHEADS * NCHUNK), dim3(256), 0, stream>>>(xc, dt_soft, xdtT);
  btr_kernel<<<dim3(NBATCH * (SEQ / 128)), dim3(256), 0, stream>>>(xc, BT);

  // SSD
  ssd_states_kernel<<<dim3(NBATCH * NCHUNK * NHEADS), dim3(256), 0, stream>>>(BT, xdtT, Acs, states);
  ssd_scan_kernel<<<dim3(NBATCH * NHEADS * 8), dim3(256), 0, stream>>>(states, cdecay, prevb);
  ssd_y_kernel<<<dim3(NBATCH * NCHUNK * NHEADS), dim3(256), 0, stream>>>(xc, xdtT, prevb, Acs, Dv, Yb);

  // gated RMSNorm (Yb bf16 -> yn; yn aliases prevb which is dead now)
  norm_kernel<<<dim3(BL), dim3(256), 0, stream>>>(Yb, zx, norm_w, yn);

  // GEMM2: out[BL][DMODEL](f32) = yn @ wout_bf^T   (BM=128, 256 blocks, R4 schedule)
  gemm256_kernel<4, false><<<dim3((DMODEL / 256) * (BL / 128)), dim3(512), 0, stream>>>(
      yn, wout_bf, out, BL, DMODEL, DINNER, DMODEL / 256);
}

// Round 10
// 545.589 us; speedup vs baseline: 1.1020x; 1.0270x over previous
//
#include <hip/hip_runtime.h>
#include <cstdint>
#include <cstddef>

#define SEQ     2048
#define NBATCH  2
#define BL      (NBATCH*SEQ)     // 4096
#define DMODEL  2048
#define DINNER  4096
#define DSTATE  128
#define HEADDIM 64
#define NHEADS  64
#define DXBC    4352
#define DPROJ   8512
#define NPAD    8704             // padded D_IN_PROJ (34*256)
#define NCHUNK  16
#define CHUNKL  128

typedef __bf16 bf16x8_t __attribute__((ext_vector_type(8)));
typedef float f32x4_t __attribute__((ext_vector_type(4)));
typedef unsigned short u16x8_t __attribute__((ext_vector_type(8)));
typedef unsigned short u16x4_t __attribute__((ext_vector_type(4)));
typedef __attribute__((address_space(1))) unsigned int as1_u32;
typedef __attribute__((address_space(3))) unsigned int as3_u32;

__device__ __forceinline__ unsigned short f2bf(float f) {
  unsigned u = __builtin_bit_cast(unsigned, f);
  u += 0x7FFFu + ((u >> 16) & 1u);
  return (unsigned short)(u >> 16);
}
__device__ __forceinline__ float bf2f(unsigned short h) {
  unsigned u = ((unsigned)h) << 16;
  return __builtin_bit_cast(float, u);
}
__device__ __forceinline__ void gload16(const void* g, void* l) {
  __builtin_amdgcn_global_load_lds((const as1_u32*)g, (as3_u32*)l, 16, 0, 0);
}
__device__ __forceinline__ f32x4_t mfma16(u16x8_t a, u16x8_t b, f32x4_t c) {
  return __builtin_amdgcn_mfma_f32_16x16x32_bf16(
      __builtin_bit_cast(bf16x8_t, a), __builtin_bit_cast(bf16x8_t, b), c, 0, 0, 0);
}
__device__ __forceinline__ float siluf(float x) { return x / (1.f + __expf(-x)); }

// -------- merged convert: u -> u_bf  |  W_in -> win_bf (zero-padded rows) --------
#define GB_U   (BL * DMODEL / 4 / 256)          // 8192
#define GB_WIN (NPAD * DMODEL / 4 / 256)        // 17408
__global__ __launch_bounds__(256) void cvt_uw_kernel(const float* __restrict__ u,
                                                     unsigned short* __restrict__ u_bf,
                                                     const float* __restrict__ W_in,
                                                     unsigned short* __restrict__ win_bf) {
  int blk = blockIdx.x;
  if (blk < GB_U) {
    int idx = (blk * 256 + threadIdx.x) * 4;
    float4 v = *(const float4*)&u[idx];
    u16x4_t o; o[0] = f2bf(v.x); o[1] = f2bf(v.y); o[2] = f2bf(v.z); o[3] = f2bf(v.w);
    *(u16x4_t*)&u_bf[idx] = o;
  } else {
    int idx = ((blk - GB_U) * 256 + threadIdx.x) * 4;
    int e = idx / DMODEL;
    u16x4_t o;
    if (e < DPROJ) {
      float4 v = *(const float4*)&W_in[idx];
      o[0] = f2bf(v.x); o[1] = f2bf(v.y); o[2] = f2bf(v.z); o[3] = f2bf(v.w);
    } else {
      o[0] = 0; o[1] = 0; o[2] = 0; o[3] = 0;
    }
    *(u16x4_t*)&win_bf[idx] = o;
  }
}

// ---------------- GEMM: C[M][N] = A[M][K] * B[N][K]^T, bf16 in ----------------
// R4-measured-best schedule (179 us, MfmaUtil 35%, 0 bank conflicts):
// BM = 32*WM (GEMM1: 256, GEMM2: 128), BN = 256, BK = 32, 8 waves (2M x 4N),
// 4-buffer LDS ring, counted vmcnt (2 tiles in flight, never 0 mid-loop),
// XOR swizzle for 64B rows, one barrier per K-tile.
template <int WM, bool BF16OUT>
__global__ __launch_bounds__(512, 2) void gemm256_kernel(const unsigned short* __restrict__ A,
                                                         const unsigned short* __restrict__ B,
                                                         void* __restrict__ Cp,
                                                         int M, int N, int K, int gx) {
  constexpr int BM  = 32 * WM;
  constexpr int AUB = BM * 64;          // A-unit bytes per K-tile
  constexpr int BUB = 16384;            // B-unit bytes (256 rows x 64B)
  constexpr int BUF = AUB + BUB;
  constexpr int LA  = AUB / 8192;       // gload instrs per thread, A unit
  constexpr int LB  = 2;
  constexpr int LT  = LA + LB;          // loads per tile
  __shared__ __attribute__((aligned(16))) char lds[4 * BUF];

  const int nwg = gridDim.x;
  const int q8 = nwg >> 3;
  const int lid = blockIdx.x;
  const int newid = (lid & 7) * q8 + (lid >> 3);     // bijective XCD chunking
  const int band = newid / (gx * 4);
  const int idx  = newid % (gx * 4);
  const int n0 = (idx >> 2) * 256;
  const int m0 = (band * 4 + (idx & 3)) * BM;

  const int t = threadIdx.x, lane = t & 63, w = t >> 6;
  const int wm = w >> 2, wn = w & 3;                 // 2 x 4 waves
  const int NK = K >> 5;
  const int kslot = (lane >> 4) * 16;                // 16B col-slot

  f32x4_t acc[WM][4];
#pragma unroll
  for (int i = 0; i < WM; ++i)
#pragma unroll
    for (int j = 0; j < 4; ++j) acc[i][j] = (f32x4_t){0.f, 0.f, 0.f, 0.f};

  auto stage_unit = [&](int u) {
    if (u >= 2 * NK) return;
    const int Tt = u >> 1;
    char* base = lds + (Tt & 3) * BUF + ((u & 1) ? AUB : 0);
    const unsigned short* G = (u & 1) ? B : A;
    const int g0 = (u & 1) ? n0 : m0;
    const int k0 = Tt << 5;
    if (u & 1) {
#pragma unroll
      for (int i = 0; i < LB; ++i) {
        int o = i * 8192 + t * 16;
        int row = o >> 6;
        int cb = (o & 63) ^ (((row >> 1) & 3) << 4);     // inverse-swizzle source
        gload16(&G[(size_t)(g0 + row) * K + k0 + (cb >> 1)], base + o);
      }
    } else {
#pragma unroll
      for (int i = 0; i < LA; ++i) {
        int o = i * 8192 + t * 16;
        int row = o >> 6;
        int cb = (o & 63) ^ (((row >> 1) & 3) << 4);
        gload16(&G[(size_t)(g0 + row) * K + k0 + (cb >> 1)], base + o);
      }
    }
  };
  auto rdA = [&](int bq, int mr) -> u16x8_t {
    int row = wm * (BM / 2) + mr * 16 + (lane & 15);
    int byte = bq * BUF + row * 64 + (kslot ^ (((row >> 1) & 3) << 4));
    return *(const u16x8_t*)(lds + byte);
  };
  auto rdB = [&](int bq, int nr) -> u16x8_t {
    int row = wn * 64 + nr * 16 + (lane & 15);
    int byte = bq * BUF + AUB + row * 64 + (kslot ^ (((row >> 1) & 3) << 4));
    return *(const u16x8_t*)(lds + byte);
  };

  // prologue: tiles 0,1,2 in flight (3*LT loads)
#pragma unroll
  for (int u = 0; u < 6; ++u) stage_unit(u);

  for (int T = 0; T < NK; ++T) {
    const int bq = T & 3;
    if (T <= NK - 3)      { if constexpr (LT == 4) asm volatile("s_waitcnt vmcnt(8)" ::: "memory");
                            else                   asm volatile("s_waitcnt vmcnt(6)" ::: "memory"); }
    else if (T == NK - 2) { if constexpr (LT == 4) asm volatile("s_waitcnt vmcnt(4)" ::: "memory");
                            else                   asm volatile("s_waitcnt vmcnt(3)" ::: "memory"); }
    else                  asm volatile("s_waitcnt vmcnt(0)" ::: "memory");
    __builtin_amdgcn_s_barrier();
    asm volatile("" ::: "memory");
    __builtin_amdgcn_sched_barrier(0);

    u16x8_t af[WM], bfr[4];
    // phase 0: read A-frags + B 0,1; stage next A-unit; MFMA nr 0,1
#pragma unroll
    for (int mr = 0; mr < WM; ++mr) af[mr] = rdA(bq, mr);
    bfr[0] = rdB(bq, 0);
    bfr[1] = rdB(bq, 1);
    stage_unit(2 * T + 6);
    __builtin_amdgcn_s_setprio(1);
#pragma unroll
    for (int mr = 0; mr < WM; ++mr) {
      acc[mr][0] = mfma16(af[mr], bfr[0], acc[mr][0]);
      acc[mr][1] = mfma16(af[mr], bfr[1], acc[mr][1]);
    }
    __builtin_amdgcn_s_setprio(0);
    // phase 1: read B 2,3; stage next B-unit; MFMA nr 2,3
    bfr[2] = rdB(bq, 2);
    bfr[3] = rdB(bq, 3);
    stage_unit(2 * T + 7);
    __builtin_amdgcn_s_setprio(1);
#pragma unroll
    for (int mr = 0; mr < WM; ++mr) {
      acc[mr][2] = mfma16(af[mr], bfr[2], acc[mr][2]);
      acc[mr][3] = mfma16(af[mr], bfr[3], acc[mr][3]);
    }
    __builtin_amdgcn_s_setprio(0);
  }

  // epilogue
#pragma unroll
  for (int mr = 0; mr < WM; ++mr) {
    const int mbase = m0 + wm * (BM / 2) + mr * 16 + (lane >> 4) * 4;
#pragma unroll
    for (int nr = 0; nr < 4; ++nr) {
      const int n = n0 + wn * 64 + nr * 16 + (lane & 15);
#pragma unroll
      for (int r = 0; r < 4; ++r) {
        if (BF16OUT) ((unsigned short*)Cp)[(size_t)(mbase + r) * N + n] = f2bf(acc[mr][nr][r]);
        else         ((float*)Cp)[(size_t)(mbase + r) * N + n] = acc[mr][nr][r];
      }
    }
  }
}

// -------- merged post-GEMM1: W_out convert | conv+silu | dt softplus+cumsum --------
#define GB_WOUT (DMODEL * DINNER / 4 / 256)     // 8192
#define GB_CONV (BL * (DXBC / 8) / 256)         // 8704
#define GB_DT   (NBATCH * NHEADS * NCHUNK / 2)  // 1024 (2 chunks/block)
__global__ __launch_bounds__(256) void postg1_kernel(const float* __restrict__ W_out,
                                                     unsigned short* __restrict__ wout_bf,
                                                     const unsigned short* __restrict__ zx,
                                                     const float* __restrict__ conv_w,
                                                     const float* __restrict__ conv_b,
                                                     unsigned short* __restrict__ xc,
                                                     const float* __restrict__ dt_bias,
                                                     const float* __restrict__ A_log,
                                                     float* __restrict__ dt_soft,
                                                     float* __restrict__ Acs,
                                                     float* __restrict__ cdecay) {
  __shared__ float sbuf[256];
  int blk = blockIdx.x;
  int t = threadIdx.x;
  if (blk < GB_WOUT) {
    // W_out f32 -> bf16
    int idx = (blk * 256 + t) * 4;
    float4 v = *(const float4*)&W_out[idx];
    u16x4_t o; o[0] = f2bf(v.x); o[1] = f2bf(v.y); o[2] = f2bf(v.z); o[3] = f2bf(v.w);
    *(u16x4_t*)&wout_bf[idx] = o;
  } else if (blk < GB_WOUT + GB_CONV) {
    // depthwise causal conv + silu, 8 channels/thread
    int idx = (blk - GB_WOUT) * 256 + t;
    int e8 = (idx % (DXBC / 8)) * 8;
    int bl = idx / (DXBC / 8);
    int l = bl % SEQ, b = bl / SEQ;
    float acc[8];
#pragma unroll
    for (int j = 0; j < 8; ++j) acc[j] = conv_b[e8 + j];
    const unsigned short* zrow = zx + (size_t)b * SEQ * NPAD + DINNER + e8;
#pragma unroll
    for (int wi = 0; wi < 4; ++wi) {
      int ll = l - 3 + wi;
      if (ll >= 0) {
        u16x8_t v = *(const u16x8_t*)(zrow + (size_t)ll * NPAD);
#pragma unroll
        for (int j = 0; j < 8; ++j) acc[j] += bf2f(v[j]) * conv_w[(e8 + j) * 4 + wi];
      }
    }
    u16x8_t o;
#pragma unroll
    for (int j = 0; j < 8; ++j) o[j] = f2bf(siluf(acc[j]));
    *(u16x8_t*)(xc + (size_t)bl * DXBC + e8) = o;
  } else {
    // dt softplus + per-chunk cumsum; 2 independent chunks per block
    int id = (blk - GB_WOUT - GB_CONV) * 2 + (t >> 7);   // global chunk instance
    int i = t & 127;
    int c = id & 15, h = (id >> 4) & 63, b = id >> 10;
    int l = c * CHUNKL + i;
    float raw = bf2f(zx[((size_t)b * SEQ + l) * NPAD + (DINNER + DXBC) + h]) + dt_bias[h];
    float dt = (raw > 20.f) ? raw : log1pf(__expf(raw));
    dt_soft[((size_t)b * 64 + h) * SEQ + l] = dt;
    float A = -__expf(A_log[h]);
    float* sb = sbuf + (t >> 7) * 128;
    sb[i] = dt * A;
    __syncthreads();
    for (int ofs = 1; ofs < 128; ofs <<= 1) {
      float v = (i >= ofs) ? sb[i - ofs] : 0.f;
      __syncthreads();
      sb[i] += v;
      __syncthreads();
    }
    float cs = sb[i];
    Acs[(((size_t)b * 64 + h) * 16 + c) * 128 + i] = cs;
    if (i == 127) cdecay[((size_t)b * 64 + h) * 16 + c] = __expf(cs);
  }
}

// -------- merged xdt^T builder | B transpose --------
#define GB_XDT (NBATCH * NHEADS * NCHUNK)       // 2048
__global__ __launch_bounds__(256) void xdtbtr_kernel(const unsigned short* __restrict__ xc,
                                                     const float* __restrict__ dt_soft,
                                                     unsigned short* __restrict__ xdtT,
                                                     unsigned short* __restrict__ BT) {
  __shared__ __attribute__((aligned(16))) char smem[33536];
  int blk = blockIdx.x;
  int t = threadIdx.x;
  if (blk < GB_XDT) {
    // xdtT[b][h][p][l] = x[b,l,h*64+p]*dt
    int lt = blk & 15, h = (blk >> 4) & 63, b = blk >> 10;
    unsigned short (*tile)[66] = (unsigned short(*)[66])smem;      // 16896 B
    float* dts = (float*)(smem + 16896);                            // 512 B
    const unsigned short* xg = xc + ((size_t)b * SEQ + lt * 128) * DXBC + h * 64;
#pragma unroll
    for (int k = 0; k < 32; ++k) {
      int idx = t + k * 256;
      int row = idx >> 6, col = idx & 63;
      tile[row][col] = xg[(size_t)row * DXBC + col];
    }
    if (t < 128) dts[t] = dt_soft[((size_t)b * 64 + h) * SEQ + lt * 128 + t];
    __syncthreads();
    unsigned short* xo = xdtT + (((size_t)b * 64 + h) * 64) * SEQ + lt * 128;
#pragma unroll
    for (int k = 0; k < 32; ++k) {
      int idx = t + k * 256;
      int p = idx >> 7, j = idx & 127;
      xo[(size_t)p * SEQ + j] = f2bf(bf2f(tile[j][p]) * dts[j]);
    }
  } else {
    // BT[b][n][l] from xc B-part
    int bb = blk - GB_XDT;
    int lt = bb & 15, b = bb >> 4;
    unsigned short (*tile)[129] = (unsigned short(*)[129])smem;     // 33024 B
    const unsigned short* src = xc + ((size_t)b * SEQ + lt * 128) * DXBC + DINNER;
#pragma unroll
    for (int k = 0; k < 64; ++k) {
      int idx = t + k * 256;
      int j = idx >> 7, n = idx & 127;
      tile[j][n] = src[(size_t)j * DXBC + n];
    }
    __syncthreads();
    unsigned short* dst = BT + (size_t)b * 128 * SEQ + lt * 128;
#pragma unroll
    for (int k = 0; k < 64; ++k) {
      int idx = t + k * 256;
      int n = idx >> 7, j = idx & 127;
      dst[(size_t)n * SEQ + j] = tile[j][n];
    }
  }
}

// -------- SSD per-chunk states (bf16 out): states[b][c][h][p][n] --------
__global__ __launch_bounds__(256) void ssd_states_kernel(const unsigned short* __restrict__ BT,
                                                         const unsigned short* __restrict__ xdtT,
                                                         const float* __restrict__ Acs,
                                                         unsigned short* __restrict__ states) {
  int blk = blockIdx.x;                       // ((b*16+c)*64+h)
  int h = blk & 63, c = (blk >> 6) & 15, b = blk >> 10;
  __shared__ unsigned short BTs[128 * 128];   // [n][j]
  __shared__ unsigned short xs[64 * 128];     // [p][j]
  __shared__ float dec[128];
  int t = threadIdx.x, lane = t & 63, w = t >> 6, wr = w >> 1, wc = w & 1;
  int srow = t >> 4, scol = (t & 15) * 8;
  const unsigned short* BTb = BT + (size_t)b * 128 * SEQ + c * 128;
#pragma unroll
  for (int s = 0; s < 8; ++s) {
    int r = s * 16 + srow;
    gload16(&BTb[(size_t)r * SEQ + scol], &BTs[r * 128 + scol]);
  }
  const unsigned short* xb = xdtT + (((size_t)b * 64 + h) * 64) * SEQ + c * 128;
#pragma unroll
  for (int s = 0; s < 4; ++s) {
    int r = s * 16 + srow;
    gload16(&xb[(size_t)r * SEQ + scol], &xs[r * 128 + scol]);
  }
  const float* acsr = Acs + (((size_t)b * 64 + h) * 16 + c) * 128;
  float alast = acsr[127];
  if (t < 128) dec[t] = __expf(alast - acsr[t]);
  __syncthreads();

  f32x4_t acc[2][4];
#pragma unroll
  for (int i = 0; i < 2; ++i)
#pragma unroll
    for (int j = 0; j < 4; ++j) acc[i][j] = (f32x4_t){0.f, 0.f, 0.f, 0.f};
#pragma unroll
  for (int ks = 0; ks < 4; ++ks) {
    const int kk = ks * 32 + (lane >> 4) * 8;
    float d8[8];
#pragma unroll
    for (int e = 0; e < 8; ++e) d8[e] = dec[kk + e];
    u16x8_t af[2], bfr[4];
#pragma unroll
    for (int i = 0; i < 2; ++i) {
      u16x8_t raw = *(const u16x8_t*)&xs[(wr * 32 + i * 16 + (lane & 15)) * 128 + kk];
      u16x8_t sc;
#pragma unroll
      for (int e = 0; e < 8; ++e) sc[e] = f2bf(bf2f(raw[e]) * d8[e]);
      af[i] = sc;
    }
#pragma unroll
    for (int j = 0; j < 4; ++j)
      bfr[j] = *(const u16x8_t*)&BTs[(wc * 64 + j * 16 + (lane & 15)) * 128 + kk];
#pragma unroll
    for (int i = 0; i < 2; ++i)
#pragma unroll
      for (int j = 0; j < 4; ++j) acc[i][j] = mfma16(af[i], bfr[j], acc[i][j]);
  }
  unsigned short* so = states + ((((size_t)b * 16 + c) * 64 + h) * 64) * 128;
#pragma unroll
  for (int i = 0; i < 2; ++i) {
    int pbase = wr * 32 + i * 16 + (lane >> 4) * 4;
#pragma unroll
    for (int j = 0; j < 4; ++j) {
      int n = wc * 64 + j * 16 + (lane & 15);
#pragma unroll
      for (int r = 0; r < 4; ++r) so[(size_t)(pbase + r) * 128 + n] = f2bf(acc[i][j][r]);
    }
  }
}

// ------ inter-chunk scan: all 16 chunk loads upfront (one latency), vec u16x4 ------
__global__ __launch_bounds__(256) void ssd_scan_kernel(const unsigned short* __restrict__ states,
                                                       const float* __restrict__ cdecay,
                                                       unsigned short* __restrict__ prevb) {
  int blk = blockIdx.x;                       // ((b*64+h)*8 + s)
  int s = blk & 7, h = (blk >> 3) & 63, b = blk >> 9;
  int t = threadIdx.x;
  const size_t eoff = (size_t)s * 1024 + t * 4;     // 4 consecutive elems/thread
  const float* cd = cdecay + ((size_t)b * 64 + h) * 16;
  u16x4_t vals[16];
#pragma unroll
  for (int c = 0; c < 16; ++c) {
    const unsigned short* sp = states + (((size_t)(b * 16 + c) * 64 + h) * 64) * 128 + eoff;
    vals[c] = *(const u16x4_t*)sp;               // independent; all issued upfront
  }
  float carry[4] = {0.f, 0.f, 0.f, 0.f};
#pragma unroll
  for (int c = 0; c < 16; ++c) {
    unsigned short* pp = prevb + (((size_t)(b * 16 + c) * 64 + h) * 64) * 128 + eoff;
    u16x4_t o;
#pragma unroll
    for (int k = 0; k < 4; ++k) o[k] = f2bf(carry[k]);
    *(u16x4_t*)pp = o;
    float d = cd[c];
#pragma unroll
    for (int k = 0; k < 4; ++k) carry[k] = carry[k] * d + bf2f(vals[c][k]);
  }
}

// ---------------- SSD Y = Y_diag + Y_off + D*x (bf16 out) ----------------
// LDS = Bs+Cs+xs = exactly 80 KB -> 2 blocks/CU. prev fragments prefetched
// direct global->register (identity layout); acs read from L1-hot global.
__global__ __launch_bounds__(256) void ssd_y_kernel(const unsigned short* __restrict__ xc,
                                                    const unsigned short* __restrict__ xdtT,
                                                    const unsigned short* __restrict__ prevb,
                                                    const float* __restrict__ Acs,
                                                    const float* __restrict__ Dp,
                                                    unsigned short* __restrict__ Y) {
  int blk = blockIdx.x;                       // ((b*16+c)*64+h)
  int h = blk & 63, c = (blk >> 6) & 15, b = blk >> 10;
  __shared__ unsigned short Bs[128 * 128];    // [j][n], reused as M[i][j]
  __shared__ unsigned short Cs[128 * 128];    // [i][n]
  __shared__ unsigned short xs[64 * 128];     // [p][j]
  int t = threadIdx.x, lane = t & 63, w = t >> 6, wr = w >> 1, wc = w & 1;
  int srow = t >> 4, scol = (t & 15) * 8;
  const unsigned short* Bg = xc + ((size_t)b * SEQ + c * 128) * DXBC + DINNER;
  const unsigned short* Cg = Bg + DSTATE;
#pragma unroll
  for (int s = 0; s < 8; ++s) {
    int r = s * 16 + srow;
    gload16(&Bg[(size_t)r * DXBC + scol], &Bs[r * 128 + scol]);
    gload16(&Cg[(size_t)r * DXBC + scol], &Cs[r * 128 + scol]);
  }
  const unsigned short* xg = xdtT + (((size_t)b * 64 + h) * 64) * SEQ + c * 128;
#pragma unroll
  for (int s = 0; s < 4; ++s) {
    int r = s * 16 + srow;
    gload16(&xg[(size_t)r * SEQ + scol], &xs[r * 128 + scol]);
  }
  // prefetch prev fragments straight to registers (same indices the old LDS path used)
  const unsigned short* pg = prevb + ((((size_t)b * 16 + c) * 64 + h) * 64) * 128;
  u16x8_t pf_all[4][2];
#pragma unroll
  for (int ks = 0; ks < 4; ++ks) {
    const int kk = ks * 32 + (lane >> 4) * 8;
#pragma unroll
    for (int j = 0; j < 2; ++j)
      pf_all[ks][j] = *(const u16x8_t*)&pg[(size_t)(wc * 32 + j * 16 + (lane & 15)) * 128 + kk];
  }
  const float* acsr = Acs + (((size_t)b * 64 + h) * 16 + c) * 128;
  __syncthreads();

  // 1) CB^T: cbt -> D[m=j][n=i] = sum_n B[j,n] C[i,n]
  f32x4_t cbt[4][4];
#pragma unroll
  for (int i = 0; i < 4; ++i)
#pragma unroll
    for (int j = 0; j < 4; ++j) cbt[i][j] = (f32x4_t){0.f, 0.f, 0.f, 0.f};
#pragma unroll
  for (int ks = 0; ks < 4; ++ks) {
    const int kk = ks * 32 + (lane >> 4) * 8;
    u16x8_t af[4], bfr[4];
#pragma unroll
    for (int i = 0; i < 4; ++i) {
      af[i]  = *(const u16x8_t*)&Bs[(wr * 64 + i * 16 + (lane & 15)) * 128 + kk];
      bfr[i] = *(const u16x8_t*)&Cs[(wc * 64 + i * 16 + (lane & 15)) * 128 + kk];
    }
#pragma unroll
    for (int i = 0; i < 4; ++i)
#pragma unroll
      for (int j = 0; j < 4; ++j) cbt[i][j] = mfma16(af[i], bfr[j], cbt[i][j]);
  }
  __syncthreads();   // all waves done reading Bs before M overwrites it
  // build M[i][j] = (i>=j) ? CB * exp(acs[i]-acs[j]) : 0   (stored into Bs)
#pragma unroll
  for (int fi = 0; fi < 4; ++fi) {
#pragma unroll
    for (int fj = 0; fj < 4; ++fj) {
      int i = wc * 64 + fj * 16 + (lane & 15);
      int jb = wr * 64 + fi * 16 + (lane >> 4) * 4;
      float ai = acsr[i];
      u16x4_t m4;
#pragma unroll
      for (int r = 0; r < 4; ++r) {
        int j = jb + r;
        float v = (i >= j) ? cbt[fi][fj][r] * __expf(ai - acsr[j]) : 0.f;
        m4[r] = f2bf(v);
      }
      *(u16x4_t*)&Bs[i * 128 + jb] = m4;
    }
  }
  __syncthreads();

  // 2) Y_diag[i][p] = sum_j M[i,j] xdtT[p,j] ; 3) Y_off[i][p] = sum_n C[i,n] prev[p,n]
  f32x4_t accY[4][2], accO[4][2];
#pragma unroll
  for (int i = 0; i < 4; ++i)
#pragma unroll
    for (int j = 0; j < 2; ++j) {
      accY[i][j] = (f32x4_t){0.f, 0.f, 0.f, 0.f};
      accO[i][j] = (f32x4_t){0.f, 0.f, 0.f, 0.f};
    }
#pragma unroll
  for (int ks = 0; ks < 4; ++ks) {
    const int kk = ks * 32 + (lane >> 4) * 8;
    u16x8_t af[4], bfr[2], cf[4];
#pragma unroll
    for (int i = 0; i < 4; ++i) {
      af[i] = *(const u16x8_t*)&Bs[(wr * 64 + i * 16 + (lane & 15)) * 128 + kk];
      cf[i] = *(const u16x8_t*)&Cs[(wr * 64 + i * 16 + (lane & 15)) * 128 + kk];
    }
#pragma unroll
    for (int j = 0; j < 2; ++j)
      bfr[j] = *(const u16x8_t*)&xs[(wc * 32 + j * 16 + (lane & 15)) * 128 + kk];
#pragma unroll
    for (int i = 0; i < 4; ++i)
#pragma unroll
      for (int j = 0; j < 2; ++j) {
        accY[i][j] = mfma16(af[i], bfr[j], accY[i][j]);
        accO[i][j] = mfma16(cf[i], pf_all[ks][j], accO[i][j]);
      }
  }
  // epilogue
  float Dh = Dp[h];
  unsigned short* Yo = Y + ((size_t)b * SEQ + c * 128) * DINNER + h * 64;
  const unsigned short* xo = xc + ((size_t)b * SEQ + c * 128) * DXBC + h * 64;
#pragma unroll
  for (int fi = 0; fi < 4; ++fi) {
    int ibase = wr * 64 + fi * 16 + (lane >> 4) * 4;
#pragma unroll
    for (int r = 0; r < 4; ++r) {
      int i = ibase + r;
      float esc = __expf(acsr[i]);
#pragma unroll
      for (int fj = 0; fj < 2; ++fj) {
        int p = wc * 32 + fj * 16 + (lane & 15);
        float v = accY[fi][fj][r] + accO[fi][fj][r] * esc + bf2f(xo[(size_t)i * DXBC + p]) * Dh;
        Yo[(size_t)i * DINNER + p] = f2bf(v);
      }
    }
  }
}

// ---------------- gated RMSNorm (bf16 Y) -> bf16, u16x8 vectorized ----------------
__global__ __launch_bounds__(256) void norm_kernel(const unsigned short* __restrict__ Y,
                                                   const unsigned short* __restrict__ zx,
                                                   const float* __restrict__ nw,
                                                   unsigned short* __restrict__ yn) {
  int bl = blockIdx.x;
  const unsigned short* yr = Y + (size_t)bl * DINNER;
  const unsigned short* zr = zx + (size_t)bl * NPAD;
  int t = threadIdx.x;
  int base = t * 16;                       // 16 consecutive elems/thread
  u16x8_t y0 = *(const u16x8_t*)&yr[base], y1 = *(const u16x8_t*)&yr[base + 8];
  u16x8_t z0 = *(const u16x8_t*)&zr[base], z1 = *(const u16x8_t*)&zr[base + 8];
  float vals[16];
  float ss = 0.f;
#pragma unroll
  for (int k = 0; k < 8; ++k) {
    float g = bf2f(y0[k]) * siluf(bf2f(z0[k]));
    vals[k] = g; ss += g * g;
  }
#pragma unroll
  for (int k = 0; k < 8; ++k) {
    float g = bf2f(y1[k]) * siluf(bf2f(z1[k]));
    vals[8 + k] = g; ss += g * g;
  }
#pragma unroll
  for (int o = 32; o > 0; o >>= 1) ss += __shfl_down(ss, o, 64);
  __shared__ float red[4];
  if ((t & 63) == 0) red[t >> 6] = ss;
  __syncthreads();
  float tot = red[0] + red[1] + red[2] + red[3];
  float rs = rsqrtf(tot * (1.f / (float)DINNER) + 1e-5f);
  u16x8_t o0, o1;
#pragma unroll
  for (int k = 0; k < 8; ++k) {
    o0[k] = f2bf(vals[k] * rs * nw[base + k]);
    o1[k] = f2bf(vals[8 + k] * rs * nw[base + 8 + k]);
  }
  *(u16x8_t*)&yn[(size_t)bl * DINNER + base] = o0;
  *(u16x8_t*)&yn[(size_t)bl * DINNER + base + 8] = o1;
}

// ---------------- host ----------------
extern "C" void kernel_launch(void* const* d_in, const int* in_sizes, int n_in,
                              void* d_out, int out_size, void* d_ws, size_t ws_size,
                              hipStream_t stream) {
  const float* u       = (const float*)d_in[0];
  const float* W_in    = (const float*)d_in[1];
  const float* conv_w  = (const float*)d_in[2];
  const float* conv_b  = (const float*)d_in[3];
  const float* dt_bias = (const float*)d_in[4];
  const float* A_log   = (const float*)d_in[5];
  const float* Dv      = (const float*)d_in[6];
  const float* norm_w  = (const float*)d_in[7];
  const float* W_out   = (const float*)d_in[8];
  float* out = (float*)d_out;
  (void)in_sizes; (void)n_in; (void)out_size;

  // ---- byte sizes ----
  const size_t SZ_UBF    = (size_t)BL * DMODEL * 2;
  const size_t SZ_WIN    = (size_t)NPAD * DMODEL * 2;
  const size_t SZ_XDTT   = (size_t)NBATCH * NHEADS * HEADDIM * SEQ * 2;
  const size_t SZ_ZX     = (size_t)BL * NPAD * 2;
  const size_t SZ_XC     = (size_t)BL * DXBC * 2;
  const size_t SZ_BT     = (size_t)NBATCH * DSTATE * SEQ * 2;
  const size_t SZ_DTS    = (size_t)NBATCH * NHEADS * SEQ * 4;
  const size_t SZ_ACS    = (size_t)NBATCH * NHEADS * NCHUNK * 128 * 4;
  const size_t SZ_CDEC   = (size_t)NBATCH * NHEADS * NCHUNK * 4;
  const size_t SZ_STATES = (size_t)NBATCH * NCHUNK * NHEADS * HEADDIM * DSTATE * 2; // bf16; also holds Y bf16
  const size_t SZ_PREV   = (size_t)NBATCH * NCHUNK * NHEADS * HEADDIM * DSTATE * 2; // bf16; also holds yn
  const size_t REGION_A  = SZ_UBF + SZ_WIN;   // holds (u_bf,win_bf) then (xdtT,wout_bf)

  char* ws = (char*)d_ws;
  size_t off = 0;
  auto alloc = [&](size_t bytes) { char* p = ws + off; off += (bytes + 255) & ~(size_t)255; return p; };

  char* regionA = alloc(REGION_A);
  unsigned short* zx     = (unsigned short*)alloc(SZ_ZX);
  unsigned short* xc     = (unsigned short*)alloc(SZ_XC);
  unsigned short* BT     = (unsigned short*)alloc(SZ_BT);
  float* dt_soft         = (float*)alloc(SZ_DTS);
  float* Acs             = (float*)alloc(SZ_ACS);
  float* cdecay          = (float*)alloc(SZ_CDEC);
  char* statesYb         = alloc(SZ_STATES);
  char* prevYn           = alloc(SZ_PREV);
  if (off > ws_size) return;   // insufficient workspace: bail cleanly

  unsigned short* u_bf    = (unsigned short*)regionA;
  unsigned short* win_bf  = (unsigned short*)(regionA + SZ_UBF);
  unsigned short* xdtT    = (unsigned short*)regionA;
  unsigned short* wout_bf = (unsigned short*)(regionA + SZ_XDTT);
  unsigned short* states  = (unsigned short*)statesYb;
  unsigned short* Yb      = (unsigned short*)statesYb;   // bf16 Y after states dead
  unsigned short* prevb   = (unsigned short*)prevYn;
  unsigned short* yn      = (unsigned short*)prevYn;     // after prevb dead

  // merged input converts (u + W_in)
  cvt_uw_kernel<<<dim3(GB_U + GB_WIN), dim3(256), 0, stream>>>(u, u_bf, W_in, win_bf);

  // GEMM1: zx[BL][NPAD](bf16) = u_bf @ win_bf^T   (BM=256, 544 blocks, R4 schedule)
  gemm256_kernel<8, true><<<dim3((NPAD / 256) * (BL / 256)), dim3(512), 0, stream>>>(
      u_bf, win_bf, zx, BL, NPAD, DMODEL, NPAD / 256);

  // merged post-GEMM1: W_out convert | conv+silu | dt softplus+cumsum
  postg1_kernel<<<dim3(GB_WOUT + GB_CONV + GB_DT), dim3(256), 0, stream>>>(
      W_out, wout_bf, zx, conv_w, conv_b, xc, dt_bias, A_log, dt_soft, Acs, cdecay);

  // merged xdt^T + B^T
  xdtbtr_kernel<<<dim3(GB_XDT + NBATCH * (SEQ / 128)), dim3(256), 0, stream>>>(
      xc, dt_soft, xdtT, BT);

  // SSD
  ssd_states_kernel<<<dim3(NBATCH * NCHUNK * NHEADS), dim3(256), 0, stream>>>(BT, xdtT, Acs, states);
  ssd_scan_kernel<<<dim3(NBATCH * NHEADS * 8), dim3(256), 0, stream>>>(states, cdecay, prevb);
  ssd_y_kernel<<<dim3(NBATCH * NCHUNK * NHEADS), dim3(256), 0, stream>>>(xc, xdtT, prevb, Acs, Dv, Yb);

  // gated RMSNorm (Yb bf16 -> yn; yn aliases prevb which is dead now)
  norm_kernel<<<dim3(BL), dim3(256), 0, stream>>>(Yb, zx, norm_w, yn);

  // GEMM2: out[BL][DMODEL](f32) = yn @ wout_bf^T   (BM=128, 256 blocks, R4 schedule)
  gemm256_kernel<4, false><<<dim3((DMODEL / 256) * (BL / 128)), dim3(512), 0, stream>>>(
      yn, wout_bf, out, BL, DMODEL, DINNER, DMODEL / 256);
}